// Round 13
// baseline (137.503 us; speedup 1.0000x reference)
//
#include <hip/hip_runtime.h>
#include <hip/hip_bf16.h>

// GPT2 attention. B=2, S=2048, D=1024, H=16, DH=64.
// inputs (f32): x[2,2048,1024], w_attn[1024,3072], b_attn[3072], w_proj[1024,1024], b_proj[1024]
// output (f32): [2,2048,1024]

#define BB 2
#define SS 2048
#define DD 1024
#define HH 16
#define DHH 64
#define MTOK (BB * SS)        // 4096
#define N3D (3 * DD)          // 3072
// 1/sqrt(64) * log2(e): softmax runs in exp2 domain
#define QSCALE 0.18033688f

typedef __attribute__((ext_vector_type(8))) short bf16x8;
typedef __attribute__((ext_vector_type(4))) float f32x4;
typedef __attribute__((ext_vector_type(4))) short short4v;

__device__ __forceinline__ short f2bf(float f) {
  unsigned int x = __float_as_uint(f);
  unsigned int r = (x + 0x7fffu + ((x >> 16) & 1u)) >> 16;
  return (short)r;
}

__device__ __forceinline__ unsigned int cvtpk_bf16(float lo, float hi) {
  unsigned int r;
  asm("v_cvt_pk_bf16_f32 %0, %1, %2" : "=v"(r) : "v"(lo), "v"(hi));
  return r;
}

// native 2^x (v_exp_f32 IS exp2); plain exp2f() lowers to an ocml libcall.
__device__ __forceinline__ float exp2n(float x) {
  float r;
  asm("v_exp_f32 %0, %1" : "=v"(r) : "v"(x));
  return r;
}

// ---------------- cast f32 -> bf16 (vectorized x4) ----------------
__global__ void cast_bf16_k(const float* __restrict__ in, short* __restrict__ out, int n4) {
  int i = blockIdx.x * blockDim.x + threadIdx.x;
  if (i < n4) {
    float4 v = reinterpret_cast<const float4*>(in)[i];
    short4v o;
    o[0] = f2bf(v.x); o[1] = f2bf(v.y); o[2] = f2bf(v.z); o[3] = f2bf(v.w);
    reinterpret_cast<short4v*>(out)[i] = o;
  }
}

// ---------------- transpose + cast: W[K][N] f32 -> Wt[N][K] bf16 ----------------
__global__ void transpose_cast_k(const float* __restrict__ W, short* __restrict__ Wt, int K, int N) {
  __shared__ float t[32][33];
  int n0 = blockIdx.x * 32, k0 = blockIdx.y * 32;
  int tx = threadIdx.x, ty = threadIdx.y;
#pragma unroll
  for (int i = 0; i < 4; ++i)
    t[ty + 8 * i][tx] = W[(size_t)(k0 + ty + 8 * i) * N + n0 + tx];
  __syncthreads();
#pragma unroll
  for (int i = 0; i < 4; ++i)
    Wt[(size_t)(n0 + ty + 8 * i) * K + k0 + tx] = f2bf(t[tx][ty + 8 * i]);
}

// ---------------- QKV GEMM: 256x256 tile, 8 waves (2Mx4N), phase-interleaved ----------------
// M=4096 N=3072 K=1024. Grid (12,16), 512 threads. Per K-tile (BK=64): 4 phases of
// {ds_read quadrant | stage next tile piece -> raw s_barrier -> setprio+16 MFMA -> raw s_barrier}.
// Staging for tile t+1 issued at phases 0-1 (>=3 phases latency cover); the only vmcnt
// drain is the tile-boundary __syncthreads(). Both-sides XOR swizzle (pre-swizzled global
// source + linear global_load_lds dest) -- the gemm128 pattern that measures 0 conflicts.
// Epilogue: Q cols scaled by QSCALE, V cols written transposed to vtout (R11/R12 proven).
__global__ __launch_bounds__(512, 2) void gemm256_qkv_k(const short* __restrict__ A,
                                                        const short* __restrict__ Bt,
                                                        const float* __restrict__ bias,
                                                        short* __restrict__ qkv,
                                                        short* __restrict__ vtout) {
  __shared__ __align__(16) char smem[131072];
  // bytes: A-tile buf d at d*32768 (256 rows x 128B, row-XOR-swizzled 16B blocks);
  //        B-tile buf d at 65536 + d*32768 (256 n-rows x 128B).
  char* Sm = smem;
  const int K = DD;

  int tid = threadIdx.x;
  int n0 = blockIdx.x * 256, m0 = blockIdx.y * 256;
  int w = tid >> 6, lane = tid & 63;
  int wr = w >> 2, wc = w & 3;  // 2 x 4 wave grid; wave tile 128x64
  int ln16 = lane & 15, l16 = lane >> 4;
  int lr8 = lane >> 3, blkp = lane & 7;

  f32x4 acc[8][4] = {};

  // stage one 256x64 tile piece (A or B) of K-tile kt into buffer d; 4 instr/thread
  auto stageA = [&](int kt, int d) {
#pragma unroll
    for (int i = 0; i < 4; ++i) {
      int rp = i * 64 + w * 8 + lr8;
      int colE = ((blkp ^ (rp & 7)) << 3);
      __builtin_amdgcn_global_load_lds(
          (const __attribute__((address_space(1))) unsigned int*)&A[(size_t)(m0 + rp) * K + kt * 64 + colE],
          (__attribute__((address_space(3))) unsigned int*)(Sm + d * 32768 + (i * 64 + w * 8) * 128),
          16, 0, 0);
    }
  };
  auto stageB = [&](int kt, int d) {
#pragma unroll
    for (int i = 0; i < 4; ++i) {
      int rp = i * 64 + w * 8 + lr8;
      int colE = ((blkp ^ (rp & 7)) << 3);
      __builtin_amdgcn_global_load_lds(
          (const __attribute__((address_space(1))) unsigned int*)&Bt[(size_t)(n0 + rp) * K + kt * 64 + colE],
          (__attribute__((address_space(3))) unsigned int*)(Sm + 65536 + d * 32768 + (i * 64 + w * 8) * 128),
          16, 0, 0);
    }
  };

  stageA(0, 0);
  stageB(0, 0);
  __syncthreads();

#pragma unroll 1
  for (int t = 0; t < 16; ++t) {
    int d = t & 1;
    const char* Ab = Sm + d * 32768;
    const char* Bb = Sm + 65536 + d * 32768;
    bf16x8 a[4], b[4];

    // ---- phase 0: read a[mh0]+b (kk0); stage A of t+1; MFMA mh0 kk0 ----
#pragma unroll
    for (int j = 0; j < 4; ++j) {
      int row = wr * 128 + j * 16 + ln16;
      a[j] = *reinterpret_cast<const bf16x8*>(Ab + row * 128 + ((l16 ^ (row & 7)) << 4));
      int rn = wc * 64 + j * 16 + ln16;
      b[j] = *reinterpret_cast<const bf16x8*>(Bb + rn * 128 + ((l16 ^ (rn & 7)) << 4));
    }
    if (t < 15) stageA(t + 1, d ^ 1);
    __builtin_amdgcn_s_barrier();
    __builtin_amdgcn_s_setprio(1);
#pragma unroll
    for (int j = 0; j < 4; ++j)
#pragma unroll
      for (int ni = 0; ni < 4; ++ni)
        acc[j][ni] = __builtin_amdgcn_mfma_f32_16x16x32_bf16(a[j], b[ni], acc[j][ni], 0, 0, 0);
    __builtin_amdgcn_s_setprio(0);
    __builtin_amdgcn_s_barrier();

    // ---- phase 1: read a[mh1] (kk0); stage B of t+1; MFMA mh1 kk0 (b reused) ----
#pragma unroll
    for (int j = 0; j < 4; ++j) {
      int row = wr * 128 + (j + 4) * 16 + ln16;
      a[j] = *reinterpret_cast<const bf16x8*>(Ab + row * 128 + ((l16 ^ (row & 7)) << 4));
    }
    if (t < 15) stageB(t + 1, d ^ 1);
    __builtin_amdgcn_s_barrier();
    __builtin_amdgcn_s_setprio(1);
#pragma unroll
    for (int j = 0; j < 4; ++j)
#pragma unroll
      for (int ni = 0; ni < 4; ++ni)
        acc[j + 4][ni] = __builtin_amdgcn_mfma_f32_16x16x32_bf16(a[j], b[ni], acc[j + 4][ni], 0, 0, 0);
    __builtin_amdgcn_s_setprio(0);
    __builtin_amdgcn_s_barrier();

    // ---- phase 2: read a[mh0]+b (kk1); MFMA mh0 kk1 ----
#pragma unroll
    for (int j = 0; j < 4; ++j) {
      int row = wr * 128 + j * 16 + ln16;
      a[j] = *reinterpret_cast<const bf16x8*>(Ab + row * 128 + (((4 + l16) ^ (row & 7)) << 4));
      int rn = wc * 64 + j * 16 + ln16;
      b[j] = *reinterpret_cast<const bf16x8*>(Bb + rn * 128 + (((4 + l16) ^ (rn & 7)) << 4));
    }
    __builtin_amdgcn_s_barrier();
    __builtin_amdgcn_s_setprio(1);
#pragma unroll
    for (int j = 0; j < 4; ++j)
#pragma unroll
      for (int ni = 0; ni < 4; ++ni)
        acc[j][ni] = __builtin_amdgcn_mfma_f32_16x16x32_bf16(a[j], b[ni], acc[j][ni], 0, 0, 0);
    __builtin_amdgcn_s_setprio(0);
    __builtin_amdgcn_s_barrier();

    // ---- phase 3: read a[mh1] (kk1); MFMA mh1 kk1; boundary drain ----
#pragma unroll
    for (int j = 0; j < 4; ++j) {
      int row = wr * 128 + (j + 4) * 16 + ln16;
      a[j] = *reinterpret_cast<const bf16x8*>(Ab + row * 128 + (((4 + l16) ^ (row & 7)) << 4));
    }
    __builtin_amdgcn_s_setprio(1);
#pragma unroll
    for (int j = 0; j < 4; ++j)
#pragma unroll
      for (int ni = 0; ni < 4; ++ni)
        acc[j + 4][ni] = __builtin_amdgcn_mfma_f32_16x16x32_bf16(a[j], b[ni], acc[j + 4][ni], 0, 0, 0);
    __builtin_amdgcn_s_setprio(0);
    __syncthreads();  // drains vmcnt: tile t+1 stages (issued phases 0-1) landed
  }

  // ---- epilogue: bias + Q-scale + V-transpose, scalar bf16 stores (cheap via L2, R10) ----
#pragma unroll
  for (int mi = 0; mi < 8; ++mi)
#pragma unroll
    for (int ni = 0; ni < 4; ++ni)
#pragma unroll
      for (int ri = 0; ri < 4; ++ri) {
        int row = m0 + wr * 128 + mi * 16 + l16 * 4 + ri;
        int col = n0 + wc * 64 + ni * 16 + ln16;
        float v = acc[mi][ni][ri] + bias[col];
        if (n0 < DD) v *= QSCALE;  // Q block (uniform per block)
        short bv = f2bf(v);
        if (n0 >= 2 * DD) {
          int bb = row >> 11, s = row & 2047;
          vtout[(size_t)(bb * 1024 + col - 2 * DD) * SS + s] = bv;
        } else {
          qkv[(size_t)row * N3D + col] = bv;
        }
      }
}

// ---------------- proj GEMM (m97 128x128 structure): C = A * Bt^T + bias, f32 out ----------------
__global__ __launch_bounds__(256) void gemm128_proj_k(const short* __restrict__ A,
                                                      const short* __restrict__ Bt,
                                                      const float* __restrict__ bias,
                                                      float* __restrict__ Cout,
                                                      int M, int N, int K) {
  __shared__ short As[128 * 64];
  __shared__ short Bs[128 * 64];
  int tid = threadIdx.x;
  int m0 = blockIdx.y * 128, n0 = blockIdx.x * 128;
  int w = tid >> 6, lane = tid & 63;
  int wr = w >> 1, wc = w & 1;
  int ln16 = lane & 15, l16 = lane >> 4;

  f32x4 acc[4][4] = {};

  int lrow0 = w * 32 + (lane >> 3);
  int blk_p = lane & 7;

  for (int k0 = 0; k0 < K; k0 += 64) {
#pragma unroll
    for (int i = 0; i < 4; ++i) {
      int row_p = lrow0 + i * 8;
      int colE = ((blk_p ^ (row_p & 7)) << 3);
      __builtin_amdgcn_global_load_lds(
          (const __attribute__((address_space(1))) unsigned int*)&A[(size_t)(m0 + row_p) * K + k0 + colE],
          (__attribute__((address_space(3))) unsigned int*)&As[(w * 4 + i) * 512],
          16, 0, 0);
      __builtin_amdgcn_global_load_lds(
          (const __attribute__((address_space(1))) unsigned int*)&Bt[(size_t)(n0 + row_p) * K + k0 + colE],
          (__attribute__((address_space(3))) unsigned int*)&Bs[(w * 4 + i) * 512],
          16, 0, 0);
    }
    __syncthreads();
#pragma unroll
    for (int kk = 0; kk < 2; ++kk) {
      bf16x8 a[4], bfr[4];
#pragma unroll
      for (int mi = 0; mi < 4; ++mi) {
        int row = wr * 64 + mi * 16 + ln16;
        int blk = (kk * 4 + l16) ^ (row & 7);
        a[mi] = *reinterpret_cast<const bf16x8*>(&As[row * 64 + blk * 8]);
      }
#pragma unroll
      for (int ni = 0; ni < 4; ++ni) {
        int row = wc * 64 + ni * 16 + ln16;
        int blk = (kk * 4 + l16) ^ (row & 7);
        bfr[ni] = *reinterpret_cast<const bf16x8*>(&Bs[row * 64 + blk * 8]);
      }
#pragma unroll
      for (int mi = 0; mi < 4; ++mi)
#pragma unroll
        for (int ni = 0; ni < 4; ++ni)
          acc[mi][ni] = __builtin_amdgcn_mfma_f32_16x16x32_bf16(a[mi], bfr[ni], acc[mi][ni], 0, 0, 0);
    }
    __syncthreads();
  }

#pragma unroll
  for (int mi = 0; mi < 4; ++mi)
#pragma unroll
    for (int ni = 0; ni < 4; ++ni)
#pragma unroll
      for (int ri = 0; ri < 4; ++ri) {
        int row = m0 + wr * 64 + mi * 16 + l16 * 4 + ri;
        int col = n0 + wc * 64 + ni * 16 + ln16;
        Cout[(size_t)row * N + col] = acc[mi][ni][ri] + bias[col];
      }
}

// ---------------- Flash attention (R12: exp2-domain softmax, native v_exp) ----------------
// grid (16, B*H), 512 threads. Waves 0-3 (g=0): even kt; waves 4-7 (g=1): odd kt.
// Wave wq owns q-rows [wq*16, wq*16+16). Block does q-tiles 31-pj then pj (uniform work).
// Scores arrive pre-scaled by QSCALE (log2 domain). LDS 53248 B.
#define MASKV -3.0e38f
__global__ __launch_bounds__(512) void flash_attn_k(const short* __restrict__ qkv,
                                                    const short* __restrict__ vt,
                                                    short* __restrict__ ctx) {
  __shared__ __align__(16) char smem[53248];
  // [0,18432): Ks[2][64][72] ; [18432,36864): Vs[2][64][72] ; [36864,53248): Ps 8*16*64 shorts
  // (XOR-swizzled 16B blocks). Combine aliases: Od f32 dump at [0,16640), mls at [17408,17920).
  short (*Ks)[64][72] = reinterpret_cast<short(*)[64][72]>(smem);
  short (*Vs)[64][72] = reinterpret_cast<short(*)[64][72]>(smem + 18432);
  short* Psr = reinterpret_cast<short*>(smem + 36864);
  float* Od = reinterpret_cast<float*>(smem);
  float* mls = reinterpret_cast<float*>(smem + 17408);

  int tid = threadIdx.x;
  int pj = blockIdx.x;
  int bh = blockIdx.y;
  int b = bh >> 4, h = bh & 15;
  int wg = tid >> 6, lane = tid & 63;
  int g = wg >> 2, wq = wg & 3;
  int ln16 = lane & 15, l16 = lane >> 4;
  int t8 = tid & 255;
  int tb = tid >> 8;  // staging parity buffer this thread fills
  int r0 = t8 >> 3, cc0 = (t8 & 7) << 3;
  int psq = (wg << 10) + (ln16 << 6);  // Ps base (shorts) for this wave+q

  const short* kbase = qkv + (size_t)(b * SS) * N3D + DD + h * DHH;  // + s*N3D + d
  const short* vbase = vt + (size_t)(bh * DHH) * SS;                 // + d*SS + s

#pragma unroll 1
  for (int ti = 0; ti < 2; ++ti) {
    int qt = ti ? pj : 31 - pj;
    int q0 = qt * 64;

    bf16x8 qf[2];
    {
      const short* qrow = qkv + (size_t)(b * SS + q0 + wq * 16 + ln16) * N3D + h * DHH;
      qf[0] = *reinterpret_cast<const bf16x8*>(qrow + l16 * 8);
      qf[1] = *reinterpret_cast<const bf16x8*>(qrow + 32 + l16 * 8);
    }
    float m_ = -1e30f, l_ = 0.f;
    f32x4 cacc[4] = {};

    int ns = (qt + 2) >> 1;
    uint4 kr0, kr1, vr0, vr1;
    {
      int kt_s = tb <= qt ? tb : qt;
      kr0 = *reinterpret_cast<const uint4*>(kbase + (size_t)(kt_s * 64 + r0) * N3D + cc0);
      kr1 = *reinterpret_cast<const uint4*>(kbase + (size_t)(kt_s * 64 + r0 + 32) * N3D + cc0);
      vr0 = *reinterpret_cast<const uint4*>(vbase + (size_t)r0 * SS + kt_s * 64 + cc0);
      vr1 = *reinterpret_cast<const uint4*>(vbase + (size_t)(r0 + 32) * SS + kt_s * 64 + cc0);
    }

#pragma unroll 1
    for (int s = 0; s < ns; ++s) {
      *reinterpret_cast<uint4*>(&Ks[tb][r0][cc0]) = kr0;
      *reinterpret_cast<uint4*>(&Ks[tb][r0 + 32][cc0]) = kr1;
      *reinterpret_cast<uint4*>(&Vs[tb][r0][cc0]) = vr0;
      *reinterpret_cast<uint4*>(&Vs[tb][r0 + 32][cc0]) = vr1;
      __syncthreads();

      // prefetch next super-iter (clamped; latency hides under softmax+PV)
      {
        int kt_n = 2 * (s + 1) + tb;
        if (kt_n > qt) kt_n = qt;
        kr0 = *reinterpret_cast<const uint4*>(kbase + (size_t)(kt_n * 64 + r0) * N3D + cc0);
        kr1 = *reinterpret_cast<const uint4*>(kbase + (size_t)(kt_n * 64 + r0 + 32) * N3D + cc0);
        vr0 = *reinterpret_cast<const uint4*>(vbase + (size_t)r0 * SS + kt_n * 64 + cc0);
        vr1 = *reinterpret_cast<const uint4*>(vbase + (size_t)(r0 + 32) * SS + kt_n * 64 + cc0);
      }

      int kt_c = 2 * s + g;
      if (kt_c <= qt) {
        // QK^T swapped: sacc[ni][ri] = S^T[k = ni*16+l16*4+ri][q = ln16]  (log2-scaled)
        f32x4 sacc[4] = {};
#pragma unroll
        for (int kk = 0; kk < 2; ++kk)
#pragma unroll
          for (int ni = 0; ni < 4; ++ni) {
            bf16x8 kf = *reinterpret_cast<const bf16x8*>(&Ks[g][ni * 16 + ln16][kk * 32 + l16 * 8]);
            sacc[ni] = __builtin_amdgcn_mfma_f32_16x16x32_bf16(kf, qf[kk], sacc[ni], 0, 0, 0);
          }

        float p[4][4];
        float mx = MASKV;
        if (kt_c == qt) {  // diagonal tile: causal mask
          int qg = q0 + wq * 16 + ln16;
#pragma unroll
          for (int ni = 0; ni < 4; ++ni)
#pragma unroll
            for (int ri = 0; ri < 4; ++ri) {
              int kg = kt_c * 64 + ni * 16 + l16 * 4 + ri;
              float v = (kg > qg) ? MASKV : sacc[ni][ri];
              p[ni][ri] = v;
              mx = fmaxf(mx, v);
            }
        } else {
#pragma unroll
          for (int ni = 0; ni < 4; ++ni)
#pragma unroll
            for (int ri = 0; ri < 4; ++ri) {
              p[ni][ri] = sacc[ni][ri];
              mx = fmaxf(mx, sacc[ni][ri]);
            }
        }
        mx = fmaxf(mx, __shfl_xor(mx, 16));
        mx = fmaxf(mx, __shfl_xor(mx, 32));

        // defer-max (T13), log2 domain: rescale only when max grew by > 11.5
        int keep = __all(mx <= m_ + 11.5f);
        float mn = m_;
        if (!keep) {
          mn = fmaxf(m_, mx);
          float sc = exp2n(m_ - mn);
          l_ *= sc;
          float scr[4];
#pragma unroll
          for (int ri = 0; ri < 4; ++ri) scr[ri] = __shfl(sc, l16 * 4 + ri);
#pragma unroll
          for (int di = 0; di < 4; ++di)
#pragma unroll
            for (int ri = 0; ri < 4; ++ri) cacc[di][ri] *= scr[ri];
          m_ = mn;
        }

        float sum = 0.f;
#pragma unroll
        for (int ni = 0; ni < 4; ++ni)
#pragma unroll
          for (int ri = 0; ri < 4; ++ri) {
            float e = exp2n(p[ni][ri] - mn);
            p[ni][ri] = e;
            sum += e;
          }
        sum += __shfl_xor(sum, 16);
        sum += __shfl_xor(sum, 32);
        l_ += sum;

        // pack P -> Ps[wave][q=ln16][k], XOR-swizzled 16B blocks (blk ^= q&7)
#pragma unroll
        for (int ni = 0; ni < 4; ++ni) {
          uint2 u;
          u.x = cvtpk_bf16(p[ni][0], p[ni][1]);
          u.y = cvtpk_bf16(p[ni][2], p[ni][3]);
          int idx = psq + ((((ni << 1) + (l16 >> 1)) ^ (ln16 & 7)) << 3) + ((l16 & 1) << 2);
          *reinterpret_cast<uint2*>(&Psr[idx]) = u;
        }
        asm volatile("s_waitcnt lgkmcnt(0)" ::: "memory");

        // ctx += P @ V
#pragma unroll
        for (int kk = 0; kk < 2; ++kk) {
          bf16x8 pa = *reinterpret_cast<const bf16x8*>(
              &Psr[psq + ((((kk << 2) + l16) ^ (ln16 & 7)) << 3)]);
#pragma unroll
          for (int di = 0; di < 4; ++di) {
            bf16x8 vb = *reinterpret_cast<const bf16x8*>(&Vs[g][di * 16 + ln16][kk * 32 + l16 * 8]);
            cacc[di] = __builtin_amdgcn_mfma_f32_16x16x32_bf16(pa, vb, cacc[di], 0, 0, 0);
          }
        }
      }
      __syncthreads();
    }

    // ---- combine even/odd partials (aliases Ks/Vs region; all kv reads done) ----
    if (g == 1) {
      if (l16 == 0) { mls[wq * 16 + ln16] = m_; mls[64 + wq * 16 + ln16] = l_; }
#pragma unroll
      for (int di = 0; di < 4; ++di)
#pragma unroll
        for (int ri = 0; ri < 4; ++ri)
          Od[wq * 1040 + (l16 * 4 + ri) * 65 + di * 16 + ln16] = cacc[di][ri];
    }
    __syncthreads();
    if (g == 0) {
      float m1 = mls[wq * 16 + ln16], l1 = mls[64 + wq * 16 + ln16];
      float mM = fmaxf(m_, m1);
      float e0 = exp2n(m_ - mM), e1 = exp2n(m1 - mM);
      float inv = 1.f / (l_ * e0 + l1 * e1);
      float e0r[4], e1r[4], ivr[4];
#pragma unroll
      for (int ri = 0; ri < 4; ++ri) {
        int src = l16 * 4 + ri;
        e0r[ri] = __shfl(e0, src);
        e1r[ri] = __shfl(e1, src);
        ivr[ri] = __shfl(inv, src);
      }
#pragma unroll
      for (int di = 0; di < 4; ++di)
#pragma unroll
        for (int ri = 0; ri < 4; ++ri) {
          float a1 = Od[wq * 1040 + (l16 * 4 + ri) * 65 + di * 16 + ln16];
          float o = (cacc[di][ri] * e0r[ri] + a1 * e1r[ri]) * ivr[ri];
          int row = q0 + wq * 16 + l16 * 4 + ri;
          int col = h * DHH + di * 16 + ln16;
          ctx[(size_t)(b * SS + row) * DD + col] = f2bf(o);
        }
    }
    __syncthreads();
  }
}

extern "C" void kernel_launch(void* const* d_in, const int* in_sizes, int n_in,
                              void* d_out, int out_size, void* d_ws, size_t ws_size,
                              hipStream_t stream) {
  const float* x      = (const float*)d_in[0];
  const float* w_attn = (const float*)d_in[1];
  const float* b_attn = (const float*)d_in[2];
  const float* w_proj = (const float*)d_in[3];
  const float* b_proj = (const float*)d_in[4];
  float* out = (float*)d_out;

  char* ws = (char*)d_ws;
  short* xb     = (short*)(ws);                       // 8388608 B
  short* wattnT = (short*)(ws + 8388608);             // 6291456 B
  short* wprojT = (short*)(ws + 14680064);            // 2097152 B
  short* qkv    = (short*)(ws + 16777216);            // 25165824 B (V third unused)
  short* vt     = (short*)(ws + 41943040);            // 8388608 B
  short* ctx    = (short*)(ws + 50331648);            // 8388608 B

  {
    int n4 = (MTOK * DD) / 4;
    cast_bf16_k<<<(n4 + 255) / 256, 256, 0, stream>>>(x, xb, n4);
  }
  transpose_cast_k<<<dim3(N3D / 32, DD / 32), dim3(32, 8), 0, stream>>>(w_attn, wattnT, DD, N3D);
  transpose_cast_k<<<dim3(DD / 32, DD / 32), dim3(32, 8), 0, stream>>>(w_proj, wprojT, DD, DD);
  // QKV GEMM (256^2 phase-interleaved): Q (scaled) + K to qkv, V transposed to vt
  gemm256_qkv_k<<<dim3(N3D / 256, MTOK / 256), 512, 0, stream>>>(xb, wattnT, b_attn, qkv, vt);
  flash_attn_k<<<dim3(16, BB * HH), 512, 0, stream>>>(qkv, vt, ctx);
  gemm128_proj_k<<<dim3(DD / 128, MTOK / 128), 256, 0, stream>>>(ctx, wprojT, b_proj, out, MTOK, DD, DD);
}

// Round 14
// 123.526 us; speedup vs baseline: 1.1132x; 1.1132x over previous
//
#include <hip/hip_runtime.h>
#include <hip/hip_bf16.h>

// GPT2 attention. B=2, S=2048, D=1024, H=16, DH=64.
// inputs (f32): x[2,2048,1024], w_attn[1024,3072], b_attn[3072], w_proj[1024,1024], b_proj[1024]
// output (f32): [2,2048,1024]

#define BB 2
#define SS 2048
#define DD 1024
#define HH 16
#define DHH 64
#define MTOK (BB * SS)        // 4096
#define N3D (3 * DD)          // 3072
// 1/sqrt(64) * log2(e): softmax runs in exp2 domain
#define QSCALE 0.18033688f

typedef __attribute__((ext_vector_type(8))) short bf16x8;
typedef __attribute__((ext_vector_type(4))) float f32x4;
typedef __attribute__((ext_vector_type(4))) short short4v;

__device__ __forceinline__ short f2bf(float f) {
  unsigned int x = __float_as_uint(f);
  unsigned int r = (x + 0x7fffu + ((x >> 16) & 1u)) >> 16;
  return (short)r;
}

__device__ __forceinline__ unsigned int cvtpk_bf16(float lo, float hi) {
  unsigned int r;
  asm("v_cvt_pk_bf16_f32 %0, %1, %2" : "=v"(r) : "v"(lo), "v"(hi));
  return r;
}

// native 2^x (v_exp_f32 IS exp2); plain exp2f() lowers to an ocml libcall.
__device__ __forceinline__ float exp2n(float x) {
  float r;
  asm("v_exp_f32 %0, %1" : "=v"(r) : "v"(x));
  return r;
}

// ---------------- cast f32 -> bf16 (vectorized x4) ----------------
__global__ void cast_bf16_k(const float* __restrict__ in, short* __restrict__ out, int n4) {
  int i = blockIdx.x * blockDim.x + threadIdx.x;
  if (i < n4) {
    float4 v = reinterpret_cast<const float4*>(in)[i];
    short4v o;
    o[0] = f2bf(v.x); o[1] = f2bf(v.y); o[2] = f2bf(v.z); o[3] = f2bf(v.w);
    reinterpret_cast<short4v*>(out)[i] = o;
  }
}

// ---------------- transpose + cast: W[K][N] f32 -> Wt[N][K] bf16 ----------------
__global__ void transpose_cast_k(const float* __restrict__ W, short* __restrict__ Wt, int K, int N) {
  __shared__ float t[32][33];
  int n0 = blockIdx.x * 32, k0 = blockIdx.y * 32;
  int tx = threadIdx.x, ty = threadIdx.y;
#pragma unroll
  for (int i = 0; i < 4; ++i)
    t[ty + 8 * i][tx] = W[(size_t)(k0 + ty + 8 * i) * N + n0 + tx];
  __syncthreads();
#pragma unroll
  for (int i = 0; i < 4; ++i)
    Wt[(size_t)(n0 + ty + 8 * i) * K + k0 + tx] = f2bf(t[tx][ty + 8 * i]);
}

// ---------------- GEMM m97-structure: C[M][N] = A[M][K] * Bt[N][K]^T + bias ----------------
// OUTF32=0 (QKV): bf16 out; Q cols (n0<DD) pre-scaled by QSCALE; V cols (n0>=2DD) are
// written TRANSPOSED to vtout (vt[(b*1024 + col-2048)][s]) instead of qkv.
// OUTF32=1 (proj): f32 out, direct dword stores.
template <int OUTF32>
__global__ __launch_bounds__(256) void gemm128_k(const short* __restrict__ A,
                                                 const short* __restrict__ Bt,
                                                 const float* __restrict__ bias,
                                                 void* __restrict__ Cout,
                                                 short* __restrict__ vtout,
                                                 int M, int N, int K) {
  __shared__ short As[128 * 64];
  __shared__ short Bs[128 * 64];
  int tid = threadIdx.x;
  int m0 = blockIdx.y * 128, n0 = blockIdx.x * 128;
  int w = tid >> 6, lane = tid & 63;
  int wr = w >> 1, wc = w & 1;
  int ln16 = lane & 15, l16 = lane >> 4;

  f32x4 acc[4][4] = {};

  int lrow0 = w * 32 + (lane >> 3);
  int blk_p = lane & 7;

  for (int k0 = 0; k0 < K; k0 += 64) {
#pragma unroll
    for (int i = 0; i < 4; ++i) {
      int row_p = lrow0 + i * 8;
      int colE = ((blk_p ^ (row_p & 7)) << 3);
      __builtin_amdgcn_global_load_lds(
          (const __attribute__((address_space(1))) unsigned int*)&A[(size_t)(m0 + row_p) * K + k0 + colE],
          (__attribute__((address_space(3))) unsigned int*)&As[(w * 4 + i) * 512],
          16, 0, 0);
      __builtin_amdgcn_global_load_lds(
          (const __attribute__((address_space(1))) unsigned int*)&Bt[(size_t)(n0 + row_p) * K + k0 + colE],
          (__attribute__((address_space(3))) unsigned int*)&Bs[(w * 4 + i) * 512],
          16, 0, 0);
    }
    __syncthreads();
#pragma unroll
    for (int kk = 0; kk < 2; ++kk) {
      bf16x8 a[4], bfr[4];
#pragma unroll
      for (int mi = 0; mi < 4; ++mi) {
        int row = wr * 64 + mi * 16 + ln16;
        int blk = (kk * 4 + l16) ^ (row & 7);
        a[mi] = *reinterpret_cast<const bf16x8*>(&As[row * 64 + blk * 8]);
      }
#pragma unroll
      for (int ni = 0; ni < 4; ++ni) {
        int row = wc * 64 + ni * 16 + ln16;
        int blk = (kk * 4 + l16) ^ (row & 7);
        bfr[ni] = *reinterpret_cast<const bf16x8*>(&Bs[row * 64 + blk * 8]);
      }
#pragma unroll
      for (int mi = 0; mi < 4; ++mi)
#pragma unroll
        for (int ni = 0; ni < 4; ++ni)
          acc[mi][ni] = __builtin_amdgcn_mfma_f32_16x16x32_bf16(a[mi], bfr[ni], acc[mi][ni], 0, 0, 0);
    }
    __syncthreads();
  }

#pragma unroll
  for (int mi = 0; mi < 4; ++mi)
#pragma unroll
    for (int ni = 0; ni < 4; ++ni)
#pragma unroll
      for (int ri = 0; ri < 4; ++ri) {
        int row = m0 + wr * 64 + mi * 16 + l16 * 4 + ri;
        int col = n0 + wc * 64 + ni * 16 + ln16;
        float v = acc[mi][ni][ri] + bias[col];
        if (OUTF32) {
          reinterpret_cast<float*>(Cout)[(size_t)row * N + col] = v;
        } else {
          if (n0 < DD) v *= QSCALE;  // Q block (uniform per block)
          short bv = f2bf(v);
          if (n0 >= 2 * DD) {
            // V block: write transposed to vt
            int bb = row >> 11, s = row & 2047;
            vtout[(size_t)(bb * 1024 + col - 2 * DD) * SS + s] = bv;
          } else {
            reinterpret_cast<short*>(Cout)[(size_t)row * N + col] = bv;
          }
        }
      }
}

// ---------------- Flash attention (R12 + XCD-chunked block swizzle) ----------------
// 1-D grid of 512 blocks, 512 threads. Chunked XCD swizzle (512%8==0, q=64): each XCD
// owns 64 consecutive work-ids = 4 whole heads -> K+V (2MB) L2-resident per XCD.
// Waves 0-3 (g=0): even kt; waves 4-7 (g=1): odd kt. Wave wq owns q-rows
// [wq*16, wq*16+16). Block does q-tiles 31-pj then pj (uniform work).
// Scores arrive pre-scaled by QSCALE (log2 domain). LDS 53248 B.
#define MASKV -3.0e38f
__global__ __launch_bounds__(512) void flash_attn_k(const short* __restrict__ qkv,
                                                    const short* __restrict__ vt,
                                                    short* __restrict__ ctx) {
  __shared__ __align__(16) char smem[53248];
  // [0,18432): Ks[2][64][72] ; [18432,36864): Vs[2][64][72] ; [36864,53248): Ps 8*16*64 shorts
  // (XOR-swizzled 16B blocks). Combine aliases: Od f32 dump at [0,16640), mls at [17408,17920).
  short (*Ks)[64][72] = reinterpret_cast<short(*)[64][72]>(smem);
  short (*Vs)[64][72] = reinterpret_cast<short(*)[64][72]>(smem + 18432);
  short* Psr = reinterpret_cast<short*>(smem + 36864);
  float* Od = reinterpret_cast<float*>(smem);
  float* mls = reinterpret_cast<float*>(smem + 17408);

  int tid = threadIdx.x;
  // XCD-chunked swizzle: hw round-robins consecutive blockIdx across the 8 XCDs;
  // remap so each XCD gets a contiguous chunk (same-head blocks share the XCD L2).
  int orig = blockIdx.x;                    // 0..511
  int wg = (orig & 7) * 64 + (orig >> 3);   // bijective (512 % 8 == 0)
  int bh = wg >> 4;
  int pj = wg & 15;
  int b = bh >> 4, h = bh & 15;
  int wgv = tid >> 6, lane = tid & 63;
  int g = wgv >> 2, wq = wgv & 3;
  int ln16 = lane & 15, l16 = lane >> 4;
  int t8 = tid & 255;
  int tb = tid >> 8;  // staging parity buffer this thread fills
  int r0 = t8 >> 3, cc0 = (t8 & 7) << 3;
  int psq = (wgv << 10) + (ln16 << 6);  // Ps base (shorts) for this wave+q

  const short* kbase = qkv + (size_t)(b * SS) * N3D + DD + h * DHH;  // + s*N3D + d
  const short* vbase = vt + (size_t)(bh * DHH) * SS;                 // + d*SS + s

#pragma unroll 1
  for (int ti = 0; ti < 2; ++ti) {
    int qt = ti ? pj : 31 - pj;
    int q0 = qt * 64;

    bf16x8 qf[2];
    {
      const short* qrow = qkv + (size_t)(b * SS + q0 + wq * 16 + ln16) * N3D + h * DHH;
      qf[0] = *reinterpret_cast<const bf16x8*>(qrow + l16 * 8);
      qf[1] = *reinterpret_cast<const bf16x8*>(qrow + 32 + l16 * 8);
    }
    float m_ = -1e30f, l_ = 0.f;
    f32x4 cacc[4] = {};

    int ns = (qt + 2) >> 1;
    uint4 kr0, kr1, vr0, vr1;
    {
      int kt_s = tb <= qt ? tb : qt;
      kr0 = *reinterpret_cast<const uint4*>(kbase + (size_t)(kt_s * 64 + r0) * N3D + cc0);
      kr1 = *reinterpret_cast<const uint4*>(kbase + (size_t)(kt_s * 64 + r0 + 32) * N3D + cc0);
      vr0 = *reinterpret_cast<const uint4*>(vbase + (size_t)r0 * SS + kt_s * 64 + cc0);
      vr1 = *reinterpret_cast<const uint4*>(vbase + (size_t)(r0 + 32) * SS + kt_s * 64 + cc0);
    }

#pragma unroll 1
    for (int s = 0; s < ns; ++s) {
      *reinterpret_cast<uint4*>(&Ks[tb][r0][cc0]) = kr0;
      *reinterpret_cast<uint4*>(&Ks[tb][r0 + 32][cc0]) = kr1;
      *reinterpret_cast<uint4*>(&Vs[tb][r0][cc0]) = vr0;
      *reinterpret_cast<uint4*>(&Vs[tb][r0 + 32][cc0]) = vr1;
      __syncthreads();

      // prefetch next super-iter (clamped; latency hides under softmax+PV)
      {
        int kt_n = 2 * (s + 1) + tb;
        if (kt_n > qt) kt_n = qt;
        kr0 = *reinterpret_cast<const uint4*>(kbase + (size_t)(kt_n * 64 + r0) * N3D + cc0);
        kr1 = *reinterpret_cast<const uint4*>(kbase + (size_t)(kt_n * 64 + r0 + 32) * N3D + cc0);
        vr0 = *reinterpret_cast<const uint4*>(vbase + (size_t)r0 * SS + kt_n * 64 + cc0);
        vr1 = *reinterpret_cast<const uint4*>(vbase + (size_t)(r0 + 32) * SS + kt_n * 64 + cc0);
      }

      int kt_c = 2 * s + g;
      if (kt_c <= qt) {
        // QK^T swapped: sacc[ni][ri] = S^T[k = ni*16+l16*4+ri][q = ln16]  (log2-scaled)
        f32x4 sacc[4] = {};
#pragma unroll
        for (int kk = 0; kk < 2; ++kk)
#pragma unroll
          for (int ni = 0; ni < 4; ++ni) {
            bf16x8 kf = *reinterpret_cast<const bf16x8*>(&Ks[g][ni * 16 + ln16][kk * 32 + l16 * 8]);
            sacc[ni] = __builtin_amdgcn_mfma_f32_16x16x32_bf16(kf, qf[kk], sacc[ni], 0, 0, 0);
          }

        float p[4][4];
        float mx = MASKV;
        if (kt_c == qt) {  // diagonal tile: causal mask
          int qg = q0 + wq * 16 + ln16;
#pragma unroll
          for (int ni = 0; ni < 4; ++ni)
#pragma unroll
            for (int ri = 0; ri < 4; ++ri) {
              int kg = kt_c * 64 + ni * 16 + l16 * 4 + ri;
              float v = (kg > qg) ? MASKV : sacc[ni][ri];
              p[ni][ri] = v;
              mx = fmaxf(mx, v);
            }
        } else {
#pragma unroll
          for (int ni = 0; ni < 4; ++ni)
#pragma unroll
            for (int ri = 0; ri < 4; ++ri) {
              p[ni][ri] = sacc[ni][ri];
              mx = fmaxf(mx, sacc[ni][ri]);
            }
        }
        mx = fmaxf(mx, __shfl_xor(mx, 16));
        mx = fmaxf(mx, __shfl_xor(mx, 32));

        // defer-max (T13), log2 domain: rescale only when max grew by > 11.5
        int keep = __all(mx <= m_ + 11.5f);
        float mn = m_;
        if (!keep) {
          mn = fmaxf(m_, mx);
          float sc = exp2n(m_ - mn);
          l_ *= sc;
          float scr[4];
#pragma unroll
          for (int ri = 0; ri < 4; ++ri) scr[ri] = __shfl(sc, l16 * 4 + ri);
#pragma unroll
          for (int di = 0; di < 4; ++di)
#pragma unroll
            for (int ri = 0; ri < 4; ++ri) cacc[di][ri] *= scr[ri];
          m_ = mn;
        }

        float sum = 0.f;
#pragma unroll
        for (int ni = 0; ni < 4; ++ni)
#pragma unroll
          for (int ri = 0; ri < 4; ++ri) {
            float e = exp2n(p[ni][ri] - mn);
            p[ni][ri] = e;
            sum += e;
          }
        sum += __shfl_xor(sum, 16);
        sum += __shfl_xor(sum, 32);
        l_ += sum;

        // pack P -> Ps[wave][q=ln16][k], XOR-swizzled 16B blocks (blk ^= q&7)
#pragma unroll
        for (int ni = 0; ni < 4; ++ni) {
          uint2 u;
          u.x = cvtpk_bf16(p[ni][0], p[ni][1]);
          u.y = cvtpk_bf16(p[ni][2], p[ni][3]);
          int idx = psq + ((((ni << 1) + (l16 >> 1)) ^ (ln16 & 7)) << 3) + ((l16 & 1) << 2);
          *reinterpret_cast<uint2*>(&Psr[idx]) = u;
        }
        asm volatile("s_waitcnt lgkmcnt(0)" ::: "memory");

        // ctx += P @ V
#pragma unroll
        for (int kk = 0; kk < 2; ++kk) {
          bf16x8 pa = *reinterpret_cast<const bf16x8*>(
              &Psr[psq + ((((kk << 2) + l16) ^ (ln16 & 7)) << 3)]);
#pragma unroll
          for (int di = 0; di < 4; ++di) {
            bf16x8 vb = *reinterpret_cast<const bf16x8*>(&Vs[g][di * 16 + ln16][kk * 32 + l16 * 8]);
            cacc[di] = __builtin_amdgcn_mfma_f32_16x16x32_bf16(pa, vb, cacc[di], 0, 0, 0);
          }
        }
      }
      __syncthreads();
    }

    // ---- combine even/odd partials (aliases Ks/Vs region; all kv reads done) ----
    if (g == 1) {
      if (l16 == 0) { mls[wq * 16 + ln16] = m_; mls[64 + wq * 16 + ln16] = l_; }
#pragma unroll
      for (int di = 0; di < 4; ++di)
#pragma unroll
        for (int ri = 0; ri < 4; ++ri)
          Od[wq * 1040 + (l16 * 4 + ri) * 65 + di * 16 + ln16] = cacc[di][ri];
    }
    __syncthreads();
    if (g == 0) {
      float m1 = mls[wq * 16 + ln16], l1 = mls[64 + wq * 16 + ln16];
      float mM = fmaxf(m_, m1);
      float e0 = exp2n(m_ - mM), e1 = exp2n(m1 - mM);
      float inv = 1.f / (l_ * e0 + l1 * e1);
      float e0r[4], e1r[4], ivr[4];
#pragma unroll
      for (int ri = 0; ri < 4; ++ri) {
        int src = l16 * 4 + ri;
        e0r[ri] = __shfl(e0, src);
        e1r[ri] = __shfl(e1, src);
        ivr[ri] = __shfl(inv, src);
      }
#pragma unroll
      for (int di = 0; di < 4; ++di)
#pragma unroll
        for (int ri = 0; ri < 4; ++ri) {
          float a1 = Od[wq * 1040 + (l16 * 4 + ri) * 65 + di * 16 + ln16];
          float o = (cacc[di][ri] * e0r[ri] + a1 * e1r[ri]) * ivr[ri];
          int row = q0 + wq * 16 + l16 * 4 + ri;
          int col = h * DHH + di * 16 + ln16;
          ctx[(size_t)(b * SS + row) * DD + col] = f2bf(o);
        }
    }
    __syncthreads();
  }
}

extern "C" void kernel_launch(void* const* d_in, const int* in_sizes, int n_in,
                              void* d_out, int out_size, void* d_ws, size_t ws_size,
                              hipStream_t stream) {
  const float* x      = (const float*)d_in[0];
  const float* w_attn = (const float*)d_in[1];
  const float* b_attn = (const float*)d_in[2];
  const float* w_proj = (const float*)d_in[3];
  const float* b_proj = (const float*)d_in[4];
  float* out = (float*)d_out;

  char* ws = (char*)d_ws;
  short* xb     = (short*)(ws);                       // 8388608 B
  short* wattnT = (short*)(ws + 8388608);             // 6291456 B
  short* wprojT = (short*)(ws + 14680064);            // 2097152 B
  short* qkv    = (short*)(ws + 16777216);            // 25165824 B (V third unused)
  short* vt     = (short*)(ws + 41943040);            // 8388608 B
  short* ctx    = (short*)(ws + 50331648);            // 8388608 B

  {
    int n4 = (MTOK * DD) / 4;
    cast_bf16_k<<<(n4 + 255) / 256, 256, 0, stream>>>(x, xb, n4);
  }
  transpose_cast_k<<<dim3(N3D / 32, DD / 32), dim3(32, 8), 0, stream>>>(w_attn, wattnT, DD, N3D);
  transpose_cast_k<<<dim3(DD / 32, DD / 32), dim3(32, 8), 0, stream>>>(w_proj, wprojT, DD, DD);
  // QKV GEMM (proven m97/128^2 structure): Q (scaled) + K to qkv, V transposed to vt
  gemm128_k<0><<<dim3(N3D / 128, MTOK / 128), 256, 0, stream>>>(xb, wattnT, b_attn, qkv, vt, MTOK, N3D, DD);
  flash_attn_k<<<dim3(512), 512, 0, stream>>>(qkv, vt, ctx);
  gemm128_k<1><<<dim3(DD / 128, MTOK / 128), 256, 0, stream>>>(ctx, wprojT, b_proj, out, nullptr, MTOK, DD, DD);
}

// Round 15
// 122.445 us; speedup vs baseline: 1.1230x; 1.0088x over previous
//
#include <hip/hip_runtime.h>
#include <hip/hip_bf16.h>

// GPT2 attention. B=2, S=2048, D=1024, H=16, DH=64.
// inputs (f32): x[2,2048,1024], w_attn[1024,3072], b_attn[3072], w_proj[1024,1024], b_proj[1024]
// output (f32): [2,2048,1024]

#define BB 2
#define SS 2048
#define DD 1024
#define HH 16
#define DHH 64
#define MTOK (BB * SS)        // 4096
#define N3D (3 * DD)          // 3072
// 1/sqrt(64) * log2(e): softmax runs in exp2 domain
#define QSCALE 0.18033688f

typedef __attribute__((ext_vector_type(8))) short bf16x8;
typedef __attribute__((ext_vector_type(4))) float f32x4;
typedef __attribute__((ext_vector_type(4))) short short4v;

__device__ __forceinline__ short f2bf(float f) {
  unsigned int x = __float_as_uint(f);
  unsigned int r = (x + 0x7fffu + ((x >> 16) & 1u)) >> 16;
  return (short)r;
}

__device__ __forceinline__ unsigned int cvtpk_bf16(float lo, float hi) {
  unsigned int r;
  asm("v_cvt_pk_bf16_f32 %0, %1, %2" : "=v"(r) : "v"(lo), "v"(hi));
  return r;
}

// native 2^x (v_exp_f32 IS exp2); plain exp2f() lowers to an ocml libcall.
__device__ __forceinline__ float exp2n(float x) {
  float r;
  asm("v_exp_f32 %0, %1" : "=v"(r) : "v"(x));
  return r;
}

// ---------------- cast f32 -> bf16 (vectorized x4) ----------------
__global__ void cast_bf16_k(const float* __restrict__ in, short* __restrict__ out, int n4) {
  int i = blockIdx.x * blockDim.x + threadIdx.x;
  if (i < n4) {
    float4 v = reinterpret_cast<const float4*>(in)[i];
    short4v o;
    o[0] = f2bf(v.x); o[1] = f2bf(v.y); o[2] = f2bf(v.z); o[3] = f2bf(v.w);
    reinterpret_cast<short4v*>(out)[i] = o;
  }
}

// ---------------- transpose + cast: W[K][N] f32 -> Wt[N][K] bf16 ----------------
__global__ void transpose_cast_k(const float* __restrict__ W, short* __restrict__ Wt, int K, int N) {
  __shared__ float t[32][33];
  int n0 = blockIdx.x * 32, k0 = blockIdx.y * 32;
  int tx = threadIdx.x, ty = threadIdx.y;
#pragma unroll
  for (int i = 0; i < 4; ++i)
    t[ty + 8 * i][tx] = W[(size_t)(k0 + ty + 8 * i) * N + n0 + tx];
  __syncthreads();
#pragma unroll
  for (int i = 0; i < 4; ++i)
    Wt[(size_t)(n0 + ty + 8 * i) * K + k0 + tx] = f2bf(t[tx][ty + 8 * i]);
}

// ---------------- GEMM m97-structure: C[M][N] = A[M][K] * Bt[N][K]^T + bias ----------------
// OUTF32=0 (QKV): bf16 out; Q cols (n0<DD) pre-scaled by QSCALE; V cols (n0>=2DD) are
// written TRANSPOSED to vtout (vt[(b*1024 + col-2048)][s]) instead of qkv.
// OUTF32=1 (proj): f32 out, direct dword stores.
template <int OUTF32>
__global__ __launch_bounds__(256) void gemm128_k(const short* __restrict__ A,
                                                 const short* __restrict__ Bt,
                                                 const float* __restrict__ bias,
                                                 void* __restrict__ Cout,
                                                 short* __restrict__ vtout,
                                                 int M, int N, int K) {
  __shared__ short As[128 * 64];
  __shared__ short Bs[128 * 64];
  int tid = threadIdx.x;
  int m0 = blockIdx.y * 128, n0 = blockIdx.x * 128;
  int w = tid >> 6, lane = tid & 63;
  int wr = w >> 1, wc = w & 1;
  int ln16 = lane & 15, l16 = lane >> 4;

  f32x4 acc[4][4] = {};

  int lrow0 = w * 32 + (lane >> 3);
  int blk_p = lane & 7;

  for (int k0 = 0; k0 < K; k0 += 64) {
#pragma unroll
    for (int i = 0; i < 4; ++i) {
      int row_p = lrow0 + i * 8;
      int colE = ((blk_p ^ (row_p & 7)) << 3);
      __builtin_amdgcn_global_load_lds(
          (const __attribute__((address_space(1))) unsigned int*)&A[(size_t)(m0 + row_p) * K + k0 + colE],
          (__attribute__((address_space(3))) unsigned int*)&As[(w * 4 + i) * 512],
          16, 0, 0);
      __builtin_amdgcn_global_load_lds(
          (const __attribute__((address_space(1))) unsigned int*)&Bt[(size_t)(n0 + row_p) * K + k0 + colE],
          (__attribute__((address_space(3))) unsigned int*)&Bs[(w * 4 + i) * 512],
          16, 0, 0);
    }
    __syncthreads();
#pragma unroll
    for (int kk = 0; kk < 2; ++kk) {
      bf16x8 a[4], bfr[4];
#pragma unroll
      for (int mi = 0; mi < 4; ++mi) {
        int row = wr * 64 + mi * 16 + ln16;
        int blk = (kk * 4 + l16) ^ (row & 7);
        a[mi] = *reinterpret_cast<const bf16x8*>(&As[row * 64 + blk * 8]);
      }
#pragma unroll
      for (int ni = 0; ni < 4; ++ni) {
        int row = wc * 64 + ni * 16 + ln16;
        int blk = (kk * 4 + l16) ^ (row & 7);
        bfr[ni] = *reinterpret_cast<const bf16x8*>(&Bs[row * 64 + blk * 8]);
      }
#pragma unroll
      for (int mi = 0; mi < 4; ++mi)
#pragma unroll
        for (int ni = 0; ni < 4; ++ni)
          acc[mi][ni] = __builtin_amdgcn_mfma_f32_16x16x32_bf16(a[mi], bfr[ni], acc[mi][ni], 0, 0, 0);
    }
    __syncthreads();
  }

#pragma unroll
  for (int mi = 0; mi < 4; ++mi)
#pragma unroll
    for (int ni = 0; ni < 4; ++ni)
#pragma unroll
      for (int ri = 0; ri < 4; ++ri) {
        int row = m0 + wr * 64 + mi * 16 + l16 * 4 + ri;
        int col = n0 + wc * 64 + ni * 16 + ln16;
        float v = acc[mi][ni][ri] + bias[col];
        if (OUTF32) {
          reinterpret_cast<float*>(Cout)[(size_t)row * N + col] = v;
        } else {
          if (n0 < DD) v *= QSCALE;  // Q block (uniform per block)
          short bv = f2bf(v);
          if (n0 >= 2 * DD) {
            // V block: write transposed to vt
            int bb = row >> 11, s = row & 2047;
            vtout[(size_t)(bb * 1024 + col - 2 * DD) * SS + s] = bv;
          } else {
            reinterpret_cast<short*>(Cout)[(size_t)row * N + col] = bv;
          }
        }
      }
}

// ---------------- Flash attention (R14 + l-via-ones-MFMA) ----------------
// 1-D grid of 512 blocks, 512 threads, XCD-chunked swizzle (FETCH 94->12MB proven R14).
// Waves 0-3 (g=0): even kt; waves 4-7 (g=1): odd kt. Wave wq owns q-rows
// [wq*16, wq*16+16). Block does q-tiles 31-pj then pj (uniform work).
// Row-sum l accumulated by mfma(pa, ones) into lacc (same C-layout as cacc) --
// removes 16 adds + 2 serial shfl_xor per step from the VALU path.
// Scores arrive pre-scaled by QSCALE (log2 domain). LDS 53248 B.
#define MASKV -3.0e38f
__global__ __launch_bounds__(512) void flash_attn_k(const short* __restrict__ qkv,
                                                    const short* __restrict__ vt,
                                                    short* __restrict__ ctx) {
  __shared__ __align__(16) char smem[53248];
  // [0,18432): Ks[2][64][72] ; [18432,36864): Vs[2][64][72] ; [36864,53248): Ps 8*16*64 shorts
  // (XOR-swizzled 16B blocks). Combine aliases: Od f32 dump at [0,16640), mls at [17408,17920),
  // lls (l dump, cacc-row layout) at [17920,18432).
  short (*Ks)[64][72] = reinterpret_cast<short(*)[64][72]>(smem);
  short (*Vs)[64][72] = reinterpret_cast<short(*)[64][72]>(smem + 18432);
  short* Psr = reinterpret_cast<short*>(smem + 36864);
  float* Od = reinterpret_cast<float*>(smem);
  float* mls = reinterpret_cast<float*>(smem + 17408);
  float* lls = reinterpret_cast<float*>(smem + 17920);

  int tid = threadIdx.x;
  // XCD-chunked swizzle: same-head blocks share an XCD L2.
  int orig = blockIdx.x;                    // 0..511
  int wg = (orig & 7) * 64 + (orig >> 3);   // bijective (512 % 8 == 0)
  int bh = wg >> 4;
  int pj = wg & 15;
  int b = bh >> 4, h = bh & 15;
  int wgv = tid >> 6, lane = tid & 63;
  int g = wgv >> 2, wq = wgv & 3;
  int ln16 = lane & 15, l16 = lane >> 4;
  int t8 = tid & 255;
  int tb = tid >> 8;  // staging parity buffer this thread fills
  int r0 = t8 >> 3, cc0 = (t8 & 7) << 3;
  int psq = (wgv << 10) + (ln16 << 6);  // Ps base (shorts) for this wave+q

  // all-ones bf16x8 (1.0 = 0x3F80) for the l row-sum MFMA
  bf16x8 vone;
#pragma unroll
  for (int j = 0; j < 8; ++j) vone[j] = (short)0x3F80;

  const short* kbase = qkv + (size_t)(b * SS) * N3D + DD + h * DHH;  // + s*N3D + d
  const short* vbase = vt + (size_t)(bh * DHH) * SS;                 // + d*SS + s

#pragma unroll 1
  for (int ti = 0; ti < 2; ++ti) {
    int qt = ti ? pj : 31 - pj;
    int q0 = qt * 64;

    bf16x8 qf[2];
    {
      const short* qrow = qkv + (size_t)(b * SS + q0 + wq * 16 + ln16) * N3D + h * DHH;
      qf[0] = *reinterpret_cast<const bf16x8*>(qrow + l16 * 8);
      qf[1] = *reinterpret_cast<const bf16x8*>(qrow + 32 + l16 * 8);
    }
    float m_ = -1e30f;
    f32x4 cacc[4] = {};
    f32x4 lacc = {};

    int ns = (qt + 2) >> 1;
    uint4 kr0, kr1, vr0, vr1;
    {
      int kt_s = tb <= qt ? tb : qt;
      kr0 = *reinterpret_cast<const uint4*>(kbase + (size_t)(kt_s * 64 + r0) * N3D + cc0);
      kr1 = *reinterpret_cast<const uint4*>(kbase + (size_t)(kt_s * 64 + r0 + 32) * N3D + cc0);
      vr0 = *reinterpret_cast<const uint4*>(vbase + (size_t)r0 * SS + kt_s * 64 + cc0);
      vr1 = *reinterpret_cast<const uint4*>(vbase + (size_t)(r0 + 32) * SS + kt_s * 64 + cc0);
    }

#pragma unroll 1
    for (int s = 0; s < ns; ++s) {
      *reinterpret_cast<uint4*>(&Ks[tb][r0][cc0]) = kr0;
      *reinterpret_cast<uint4*>(&Ks[tb][r0 + 32][cc0]) = kr1;
      *reinterpret_cast<uint4*>(&Vs[tb][r0][cc0]) = vr0;
      *reinterpret_cast<uint4*>(&Vs[tb][r0 + 32][cc0]) = vr1;
      __syncthreads();

      // prefetch next super-iter (clamped; latency hides under softmax+PV)
      {
        int kt_n = 2 * (s + 1) + tb;
        if (kt_n > qt) kt_n = qt;
        kr0 = *reinterpret_cast<const uint4*>(kbase + (size_t)(kt_n * 64 + r0) * N3D + cc0);
        kr1 = *reinterpret_cast<const uint4*>(kbase + (size_t)(kt_n * 64 + r0 + 32) * N3D + cc0);
        vr0 = *reinterpret_cast<const uint4*>(vbase + (size_t)r0 * SS + kt_n * 64 + cc0);
        vr1 = *reinterpret_cast<const uint4*>(vbase + (size_t)(r0 + 32) * SS + kt_n * 64 + cc0);
      }

      int kt_c = 2 * s + g;
      if (kt_c <= qt) {
        // QK^T swapped: sacc[ni][ri] = S^T[k = ni*16+l16*4+ri][q = ln16]  (log2-scaled)
        f32x4 sacc[4] = {};
#pragma unroll
        for (int kk = 0; kk < 2; ++kk)
#pragma unroll
          for (int ni = 0; ni < 4; ++ni) {
            bf16x8 kf = *reinterpret_cast<const bf16x8*>(&Ks[g][ni * 16 + ln16][kk * 32 + l16 * 8]);
            sacc[ni] = __builtin_amdgcn_mfma_f32_16x16x32_bf16(kf, qf[kk], sacc[ni], 0, 0, 0);
          }

        float p[4][4];
        float mx = MASKV;
        if (kt_c == qt) {  // diagonal tile: causal mask
          int qg = q0 + wq * 16 + ln16;
#pragma unroll
          for (int ni = 0; ni < 4; ++ni)
#pragma unroll
            for (int ri = 0; ri < 4; ++ri) {
              int kg = kt_c * 64 + ni * 16 + l16 * 4 + ri;
              float v = (kg > qg) ? MASKV : sacc[ni][ri];
              p[ni][ri] = v;
              mx = fmaxf(mx, v);
            }
        } else {
#pragma unroll
          for (int ni = 0; ni < 4; ++ni)
#pragma unroll
            for (int ri = 0; ri < 4; ++ri) {
              p[ni][ri] = sacc[ni][ri];
              mx = fmaxf(mx, sacc[ni][ri]);
            }
        }
        mx = fmaxf(mx, __shfl_xor(mx, 16));
        mx = fmaxf(mx, __shfl_xor(mx, 32));

        // defer-max (T13), log2 domain: rescale only when max grew by > 11.5
        int keep = __all(mx <= m_ + 11.5f);
        float mn = m_;
        if (!keep) {
          mn = fmaxf(m_, mx);
          float sc = exp2n(m_ - mn);
          float scr[4];
#pragma unroll
          for (int ri = 0; ri < 4; ++ri) scr[ri] = __shfl(sc, l16 * 4 + ri);
#pragma unroll
          for (int di = 0; di < 4; ++di)
#pragma unroll
            for (int ri = 0; ri < 4; ++ri) cacc[di][ri] *= scr[ri];
#pragma unroll
          for (int ri = 0; ri < 4; ++ri) lacc[ri] *= scr[ri];
          m_ = mn;
        }

#pragma unroll
        for (int ni = 0; ni < 4; ++ni)
#pragma unroll
          for (int ri = 0; ri < 4; ++ri)
            p[ni][ri] = exp2n(p[ni][ri] - mn);

        // pack P -> Ps[wave][q=ln16][k], XOR-swizzled 16B blocks (blk ^= q&7)
#pragma unroll
        for (int ni = 0; ni < 4; ++ni) {
          uint2 u;
          u.x = cvtpk_bf16(p[ni][0], p[ni][1]);
          u.y = cvtpk_bf16(p[ni][2], p[ni][3]);
          int idx = psq + ((((ni << 1) + (l16 >> 1)) ^ (ln16 & 7)) << 3) + ((l16 & 1) << 2);
          *reinterpret_cast<uint2*>(&Psr[idx]) = u;
        }
        asm volatile("s_waitcnt lgkmcnt(0)" ::: "memory");

        // ctx += P @ V ; l += P @ ones (same C-layout: row = l16*4+ri)
#pragma unroll
        for (int kk = 0; kk < 2; ++kk) {
          bf16x8 pa = *reinterpret_cast<const bf16x8*>(
              &Psr[psq + ((((kk << 2) + l16) ^ (ln16 & 7)) << 3)]);
          lacc = __builtin_amdgcn_mfma_f32_16x16x32_bf16(pa, vone, lacc, 0, 0, 0);
#pragma unroll
          for (int di = 0; di < 4; ++di) {
            bf16x8 vb = *reinterpret_cast<const bf16x8*>(&Vs[g][di * 16 + ln16][kk * 32 + l16 * 8]);
            cacc[di] = __builtin_amdgcn_mfma_f32_16x16x32_bf16(pa, vb, cacc[di], 0, 0, 0);
          }
        }
      }
      __syncthreads();
    }

    // ---- combine even/odd partials (aliases Ks/Vs region; all kv reads done) ----
    if (g == 1) {
      if (l16 == 0) mls[wq * 16 + ln16] = m_;
      if (ln16 == 0)
#pragma unroll
        for (int ri = 0; ri < 4; ++ri) lls[wq * 16 + l16 * 4 + ri] = lacc[ri];
#pragma unroll
      for (int di = 0; di < 4; ++di)
#pragma unroll
        for (int ri = 0; ri < 4; ++ri)
          Od[wq * 1040 + (l16 * 4 + ri) * 65 + di * 16 + ln16] = cacc[di][ri];
    }
    __syncthreads();
    if (g == 0) {
      float m1 = mls[wq * 16 + ln16];
      float mM = fmaxf(m_, m1);
      float e0 = exp2n(m_ - mM), e1 = exp2n(m1 - mM);
      float e0r[4], e1r[4], ivr[4];
#pragma unroll
      for (int ri = 0; ri < 4; ++ri) {
        int src = l16 * 4 + ri;
        e0r[ri] = __shfl(e0, src);
        e1r[ri] = __shfl(e1, src);
      }
#pragma unroll
      for (int ri = 0; ri < 4; ++ri) {
        float l1 = lls[wq * 16 + l16 * 4 + ri];
        ivr[ri] = 1.f / (lacc[ri] * e0r[ri] + l1 * e1r[ri]);
      }
#pragma unroll
      for (int di = 0; di < 4; ++di)
#pragma unroll
        for (int ri = 0; ri < 4; ++ri) {
          float a1 = Od[wq * 1040 + (l16 * 4 + ri) * 65 + di * 16 + ln16];
          float o = (cacc[di][ri] * e0r[ri] + a1 * e1r[ri]) * ivr[ri];
          int row = q0 + wq * 16 + l16 * 4 + ri;
          int col = h * DHH + di * 16 + ln16;
          ctx[(size_t)(b * SS + row) * DD + col] = f2bf(o);
        }
    }
    __syncthreads();
  }
}

extern "C" void kernel_launch(void* const* d_in, const int* in_sizes, int n_in,
                              void* d_out, int out_size, void* d_ws, size_t ws_size,
                              hipStream_t stream) {
  const float* x      = (const float*)d_in[0];
  const float* w_attn = (const float*)d_in[1];
  const float* b_attn = (const float*)d_in[2];
  const float* w_proj = (const float*)d_in[3];
  const float* b_proj = (const float*)d_in[4];
  float* out = (float*)d_out;

  char* ws = (char*)d_ws;
  short* xb     = (short*)(ws);                       // 8388608 B
  short* wattnT = (short*)(ws + 8388608);             // 6291456 B
  short* wprojT = (short*)(ws + 14680064);            // 2097152 B
  short* qkv    = (short*)(ws + 16777216);            // 25165824 B (V third unused)
  short* vt     = (short*)(ws + 41943040);            // 8388608 B
  short* ctx    = (short*)(ws + 50331648);            // 8388608 B

  {
    int n4 = (MTOK * DD) / 4;
    cast_bf16_k<<<(n4 + 255) / 256, 256, 0, stream>>>(x, xb, n4);
  }
  transpose_cast_k<<<dim3(N3D / 32, DD / 32), dim3(32, 8), 0, stream>>>(w_attn, wattnT, DD, N3D);
  transpose_cast_k<<<dim3(DD / 32, DD / 32), dim3(32, 8), 0, stream>>>(w_proj, wprojT, DD, DD);
  // QKV GEMM (proven m97/128^2 structure): Q (scaled) + K to qkv, V transposed to vt
  gemm128_k<0><<<dim3(N3D / 128, MTOK / 128), 256, 0, stream>>>(xb, wattnT, b_attn, qkv, vt, MTOK, N3D, DD);
  flash_attn_k<<<dim3(512), 512, 0, stream>>>(qkv, vt, ctx);
  gemm128_k<1><<<dim3(DD / 128, MTOK / 128), 256, 0, stream>>>(ctx, wprojT, b_proj, out, nullptr, MTOK, DD, DD);
}

// Round 16
// 115.536 us; speedup vs baseline: 1.1901x; 1.0598x over previous
//
#include <hip/hip_runtime.h>
#include <hip/hip_bf16.h>

// GPT2 attention. B=2, S=2048, D=1024, H=16, DH=64.
// inputs (f32): x[2,2048,1024], w_attn[1024,3072], b_attn[3072], w_proj[1024,1024], b_proj[1024]
// output (f32): [2,2048,1024]

#define BB 2
#define SS 2048
#define DD 1024
#define HH 16
#define DHH 64
#define MTOK (BB * SS)        // 4096
#define N3D (3 * DD)          // 3072
// 1/sqrt(64) * log2(e): softmax runs in exp2 domain
#define QSCALE 0.18033688f

typedef __attribute__((ext_vector_type(8))) short bf16x8;
typedef __attribute__((ext_vector_type(4))) float f32x4;
typedef __attribute__((ext_vector_type(4))) short short4v;

__device__ __forceinline__ short f2bf(float f) {
  unsigned int x = __float_as_uint(f);
  unsigned int r = (x + 0x7fffu + ((x >> 16) & 1u)) >> 16;
  return (short)r;
}

__device__ __forceinline__ unsigned int cvtpk_bf16(float lo, float hi) {
  unsigned int r;
  asm("v_cvt_pk_bf16_f32 %0, %1, %2" : "=v"(r) : "v"(lo), "v"(hi));
  return r;
}

// native 2^x (v_exp_f32 IS exp2); plain exp2f() lowers to an ocml libcall.
__device__ __forceinline__ float exp2n(float x) {
  float r;
  asm("v_exp_f32 %0, %1" : "=v"(r) : "v"(x));
  return r;
}

// ---------------- fused prep: x cast (seg A) + w_attn transpose (seg B) + w_proj transpose (seg C) ----------------
// 1-D grid of 5120 blocks x 256 threads:
//   [0,1024): x f32 -> bf16, 1024 float4/block
//   [1024,4096): w_attn [1024][3072] -> wattnT [3072][1024] bf16, 32x32 tiles (96 x 32)
//   [4096,5120): w_proj [1024][1024] -> wprojT bf16, 32x32 tiles (32 x 32)
__global__ __launch_bounds__(256) void prep_k(const float* __restrict__ x, short* __restrict__ xb,
                                              const float* __restrict__ wa, short* __restrict__ waT,
                                              const float* __restrict__ wp, short* __restrict__ wpT) {
  __shared__ float t[32][33];
  int bid = blockIdx.x, tid = threadIdx.x;
  if (bid < 1024) {
    int base = bid * 1024 + tid;
#pragma unroll
    for (int j = 0; j < 4; ++j) {
      float4 v = reinterpret_cast<const float4*>(x)[base + 256 * j];
      short4v o;
      o[0] = f2bf(v.x); o[1] = f2bf(v.y); o[2] = f2bf(v.z); o[3] = f2bf(v.w);
      reinterpret_cast<short4v*>(xb)[base + 256 * j] = o;
    }
    return;
  }
  const float* W; short* Wt; int K, N, n0, k0;
  if (bid < 4096) {
    int id = bid - 1024;
    W = wa; Wt = waT; K = 1024; N = 3072;
    n0 = (id % 96) * 32; k0 = (id / 96) * 32;
  } else {
    int id = bid - 4096;
    W = wp; Wt = wpT; K = 1024; N = 1024;
    n0 = (id & 31) * 32; k0 = (id >> 5) * 32;
  }
  int tx = tid & 31, ty = tid >> 5;
#pragma unroll
  for (int i = 0; i < 4; ++i)
    t[ty + 8 * i][tx] = W[(size_t)(k0 + ty + 8 * i) * N + n0 + tx];
  __syncthreads();
#pragma unroll
  for (int i = 0; i < 4; ++i)
    Wt[(size_t)(n0 + ty + 8 * i) * K + k0 + tx] = f2bf(t[tx][ty + 8 * i]);
}

// ---------------- GEMM m97-structure: C[M][N] = A[M][K] * Bt[N][K]^T + bias ----------------
// OUTF32=0 (QKV): bf16 out; Q cols (n0<DD) pre-scaled by QSCALE; V cols (n0>=2DD) are
// written TRANSPOSED to vtout (vt[(b*1024 + col-2048)][s]) instead of qkv.
// OUTF32=1 (proj): f32 out, direct dword stores.
template <int OUTF32>
__global__ __launch_bounds__(256) void gemm128_k(const short* __restrict__ A,
                                                 const short* __restrict__ Bt,
                                                 const float* __restrict__ bias,
                                                 void* __restrict__ Cout,
                                                 short* __restrict__ vtout,
                                                 int M, int N, int K) {
  __shared__ short As[128 * 64];
  __shared__ short Bs[128 * 64];
  int tid = threadIdx.x;
  int m0 = blockIdx.y * 128, n0 = blockIdx.x * 128;
  int w = tid >> 6, lane = tid & 63;
  int wr = w >> 1, wc = w & 1;
  int ln16 = lane & 15, l16 = lane >> 4;

  f32x4 acc[4][4] = {};

  int lrow0 = w * 32 + (lane >> 3);
  int blk_p = lane & 7;

  for (int k0 = 0; k0 < K; k0 += 64) {
#pragma unroll
    for (int i = 0; i < 4; ++i) {
      int row_p = lrow0 + i * 8;
      int colE = ((blk_p ^ (row_p & 7)) << 3);
      __builtin_amdgcn_global_load_lds(
          (const __attribute__((address_space(1))) unsigned int*)&A[(size_t)(m0 + row_p) * K + k0 + colE],
          (__attribute__((address_space(3))) unsigned int*)&As[(w * 4 + i) * 512],
          16, 0, 0);
      __builtin_amdgcn_global_load_lds(
          (const __attribute__((address_space(1))) unsigned int*)&Bt[(size_t)(n0 + row_p) * K + k0 + colE],
          (__attribute__((address_space(3))) unsigned int*)&Bs[(w * 4 + i) * 512],
          16, 0, 0);
    }
    __syncthreads();
#pragma unroll
    for (int kk = 0; kk < 2; ++kk) {
      bf16x8 a[4], bfr[4];
#pragma unroll
      for (int mi = 0; mi < 4; ++mi) {
        int row = wr * 64 + mi * 16 + ln16;
        int blk = (kk * 4 + l16) ^ (row & 7);
        a[mi] = *reinterpret_cast<const bf16x8*>(&As[row * 64 + blk * 8]);
      }
#pragma unroll
      for (int ni = 0; ni < 4; ++ni) {
        int row = wc * 64 + ni * 16 + ln16;
        int blk = (kk * 4 + l16) ^ (row & 7);
        bfr[ni] = *reinterpret_cast<const bf16x8*>(&Bs[row * 64 + blk * 8]);
      }
#pragma unroll
      for (int mi = 0; mi < 4; ++mi)
#pragma unroll
        for (int ni = 0; ni < 4; ++ni)
          acc[mi][ni] = __builtin_amdgcn_mfma_f32_16x16x32_bf16(a[mi], bfr[ni], acc[mi][ni], 0, 0, 0);
    }
    __syncthreads();
  }

#pragma unroll
  for (int mi = 0; mi < 4; ++mi)
#pragma unroll
    for (int ni = 0; ni < 4; ++ni)
#pragma unroll
      for (int ri = 0; ri < 4; ++ri) {
        int row = m0 + wr * 64 + mi * 16 + l16 * 4 + ri;
        int col = n0 + wc * 64 + ni * 16 + ln16;
        float v = acc[mi][ni][ri] + bias[col];
        if (OUTF32) {
          reinterpret_cast<float*>(Cout)[(size_t)row * N + col] = v;
        } else {
          if (n0 < DD) v *= QSCALE;  // Q block (uniform per block)
          short bv = f2bf(v);
          if (n0 >= 2 * DD) {
            // V block: write transposed to vt
            int bb = row >> 11, s = row & 2047;
            vtout[(size_t)(bb * 1024 + col - 2 * DD) * SS + s] = bv;
          } else {
            reinterpret_cast<short*>(Cout)[(size_t)row * N + col] = bv;
          }
        }
      }
}

// ---------------- Flash attention (R15 + setprio around MFMA clusters) ----------------
// 1-D grid of 512 blocks, 512 threads, XCD-chunked swizzle (FETCH 94->12MB proven R14).
// Waves 0-3 (g=0): even kt; waves 4-7 (g=1): odd kt. Wave wq owns q-rows
// [wq*16, wq*16+16). Block does q-tiles 31-pj then pj (uniform work).
// Row-sum l via mfma(pa, ones) into lacc (R15). Scores pre-scaled by QSCALE
// (log2 domain, native v_exp). LDS 53248 B.
#define MASKV -3.0e38f
__global__ __launch_bounds__(512) void flash_attn_k(const short* __restrict__ qkv,
                                                    const short* __restrict__ vt,
                                                    short* __restrict__ ctx) {
  __shared__ __align__(16) char smem[53248];
  // [0,18432): Ks[2][64][72] ; [18432,36864): Vs[2][64][72] ; [36864,53248): Ps 8*16*64 shorts
  // (XOR-swizzled 16B blocks). Combine aliases: Od f32 dump at [0,16640), mls at [17408,17920),
  // lls (l dump, cacc-row layout) at [17920,18432).
  short (*Ks)[64][72] = reinterpret_cast<short(*)[64][72]>(smem);
  short (*Vs)[64][72] = reinterpret_cast<short(*)[64][72]>(smem + 18432);
  short* Psr = reinterpret_cast<short*>(smem + 36864);
  float* Od = reinterpret_cast<float*>(smem);
  float* mls = reinterpret_cast<float*>(smem + 17408);
  float* lls = reinterpret_cast<float*>(smem + 17920);

  int tid = threadIdx.x;
  // XCD-chunked swizzle: same-head blocks share an XCD L2.
  int orig = blockIdx.x;                    // 0..511
  int wg = (orig & 7) * 64 + (orig >> 3);   // bijective (512 % 8 == 0)
  int bh = wg >> 4;
  int pj = wg & 15;
  int b = bh >> 4, h = bh & 15;
  int wgv = tid >> 6, lane = tid & 63;
  int g = wgv >> 2, wq = wgv & 3;
  int ln16 = lane & 15, l16 = lane >> 4;
  int t8 = tid & 255;
  int tb = tid >> 8;  // staging parity buffer this thread fills
  int r0 = t8 >> 3, cc0 = (t8 & 7) << 3;
  int psq = (wgv << 10) + (ln16 << 6);  // Ps base (shorts) for this wave+q

  // all-ones bf16x8 (1.0 = 0x3F80) for the l row-sum MFMA
  bf16x8 vone;
#pragma unroll
  for (int j = 0; j < 8; ++j) vone[j] = (short)0x3F80;

  const short* kbase = qkv + (size_t)(b * SS) * N3D + DD + h * DHH;  // + s*N3D + d
  const short* vbase = vt + (size_t)(bh * DHH) * SS;                 // + d*SS + s

#pragma unroll 1
  for (int ti = 0; ti < 2; ++ti) {
    int qt = ti ? pj : 31 - pj;
    int q0 = qt * 64;

    bf16x8 qf[2];
    {
      const short* qrow = qkv + (size_t)(b * SS + q0 + wq * 16 + ln16) * N3D + h * DHH;
      qf[0] = *reinterpret_cast<const bf16x8*>(qrow + l16 * 8);
      qf[1] = *reinterpret_cast<const bf16x8*>(qrow + 32 + l16 * 8);
    }
    float m_ = -1e30f;
    f32x4 cacc[4] = {};
    f32x4 lacc = {};

    int ns = (qt + 2) >> 1;
    uint4 kr0, kr1, vr0, vr1;
    {
      int kt_s = tb <= qt ? tb : qt;
      kr0 = *reinterpret_cast<const uint4*>(kbase + (size_t)(kt_s * 64 + r0) * N3D + cc0);
      kr1 = *reinterpret_cast<const uint4*>(kbase + (size_t)(kt_s * 64 + r0 + 32) * N3D + cc0);
      vr0 = *reinterpret_cast<const uint4*>(vbase + (size_t)r0 * SS + kt_s * 64 + cc0);
      vr1 = *reinterpret_cast<const uint4*>(vbase + (size_t)(r0 + 32) * SS + kt_s * 64 + cc0);
    }

#pragma unroll 1
    for (int s = 0; s < ns; ++s) {
      *reinterpret_cast<uint4*>(&Ks[tb][r0][cc0]) = kr0;
      *reinterpret_cast<uint4*>(&Ks[tb][r0 + 32][cc0]) = kr1;
      *reinterpret_cast<uint4*>(&Vs[tb][r0][cc0]) = vr0;
      *reinterpret_cast<uint4*>(&Vs[tb][r0 + 32][cc0]) = vr1;
      __syncthreads();

      // prefetch next super-iter (clamped; latency hides under softmax+PV)
      {
        int kt_n = 2 * (s + 1) + tb;
        if (kt_n > qt) kt_n = qt;
        kr0 = *reinterpret_cast<const uint4*>(kbase + (size_t)(kt_n * 64 + r0) * N3D + cc0);
        kr1 = *reinterpret_cast<const uint4*>(kbase + (size_t)(kt_n * 64 + r0 + 32) * N3D + cc0);
        vr0 = *reinterpret_cast<const uint4*>(vbase + (size_t)r0 * SS + kt_n * 64 + cc0);
        vr1 = *reinterpret_cast<const uint4*>(vbase + (size_t)(r0 + 32) * SS + kt_n * 64 + cc0);
      }

      int kt_c = 2 * s + g;
      if (kt_c <= qt) {
        // QK^T swapped: sacc[ni][ri] = S^T[k = ni*16+l16*4+ri][q = ln16]  (log2-scaled)
        f32x4 sacc[4] = {};
        __builtin_amdgcn_s_setprio(1);
#pragma unroll
        for (int kk = 0; kk < 2; ++kk)
#pragma unroll
          for (int ni = 0; ni < 4; ++ni) {
            bf16x8 kf = *reinterpret_cast<const bf16x8*>(&Ks[g][ni * 16 + ln16][kk * 32 + l16 * 8]);
            sacc[ni] = __builtin_amdgcn_mfma_f32_16x16x32_bf16(kf, qf[kk], sacc[ni], 0, 0, 0);
          }
        __builtin_amdgcn_s_setprio(0);

        float p[4][4];
        float mx = MASKV;
        if (kt_c == qt) {  // diagonal tile: causal mask
          int qg = q0 + wq * 16 + ln16;
#pragma unroll
          for (int ni = 0; ni < 4; ++ni)
#pragma unroll
            for (int ri = 0; ri < 4; ++ri) {
              int kg = kt_c * 64 + ni * 16 + l16 * 4 + ri;
              float v = (kg > qg) ? MASKV : sacc[ni][ri];
              p[ni][ri] = v;
              mx = fmaxf(mx, v);
            }
        } else {
#pragma unroll
          for (int ni = 0; ni < 4; ++ni)
#pragma unroll
            for (int ri = 0; ri < 4; ++ri) {
              p[ni][ri] = sacc[ni][ri];
              mx = fmaxf(mx, sacc[ni][ri]);
            }
        }
        mx = fmaxf(mx, __shfl_xor(mx, 16));
        mx = fmaxf(mx, __shfl_xor(mx, 32));

        // defer-max (T13), log2 domain: rescale only when max grew by > 11.5
        int keep = __all(mx <= m_ + 11.5f);
        float mn = m_;
        if (!keep) {
          mn = fmaxf(m_, mx);
          float sc = exp2n(m_ - mn);
          float scr[4];
#pragma unroll
          for (int ri = 0; ri < 4; ++ri) scr[ri] = __shfl(sc, l16 * 4 + ri);
#pragma unroll
          for (int di = 0; di < 4; ++di)
#pragma unroll
            for (int ri = 0; ri < 4; ++ri) cacc[di][ri] *= scr[ri];
#pragma unroll
          for (int ri = 0; ri < 4; ++ri) lacc[ri] *= scr[ri];
          m_ = mn;
        }

#pragma unroll
        for (int ni = 0; ni < 4; ++ni)
#pragma unroll
          for (int ri = 0; ri < 4; ++ri)
            p[ni][ri] = exp2n(p[ni][ri] - mn);

        // pack P -> Ps[wave][q=ln16][k], XOR-swizzled 16B blocks (blk ^= q&7)
#pragma unroll
        for (int ni = 0; ni < 4; ++ni) {
          uint2 u;
          u.x = cvtpk_bf16(p[ni][0], p[ni][1]);
          u.y = cvtpk_bf16(p[ni][2], p[ni][3]);
          int idx = psq + ((((ni << 1) + (l16 >> 1)) ^ (ln16 & 7)) << 3) + ((l16 & 1) << 2);
          *reinterpret_cast<uint2*>(&Psr[idx]) = u;
        }
        asm volatile("s_waitcnt lgkmcnt(0)" ::: "memory");

        // ctx += P @ V ; l += P @ ones (same C-layout: row = l16*4+ri)
        __builtin_amdgcn_s_setprio(1);
#pragma unroll
        for (int kk = 0; kk < 2; ++kk) {
          bf16x8 pa = *reinterpret_cast<const bf16x8*>(
              &Psr[psq + ((((kk << 2) + l16) ^ (ln16 & 7)) << 3)]);
          lacc = __builtin_amdgcn_mfma_f32_16x16x32_bf16(pa, vone, lacc, 0, 0, 0);
#pragma unroll
          for (int di = 0; di < 4; ++di) {
            bf16x8 vb = *reinterpret_cast<const bf16x8*>(&Vs[g][di * 16 + ln16][kk * 32 + l16 * 8]);
            cacc[di] = __builtin_amdgcn_mfma_f32_16x16x32_bf16(pa, vb, cacc[di], 0, 0, 0);
          }
        }
        __builtin_amdgcn_s_setprio(0);
      }
      __syncthreads();
    }

    // ---- combine even/odd partials (aliases Ks/Vs region; all kv reads done) ----
    if (g == 1) {
      if (l16 == 0) mls[wq * 16 + ln16] = m_;
      if (ln16 == 0)
#pragma unroll
        for (int ri = 0; ri < 4; ++ri) lls[wq * 16 + l16 * 4 + ri] = lacc[ri];
#pragma unroll
      for (int di = 0; di < 4; ++di)
#pragma unroll
        for (int ri = 0; ri < 4; ++ri)
          Od[wq * 1040 + (l16 * 4 + ri) * 65 + di * 16 + ln16] = cacc[di][ri];
    }
    __syncthreads();
    if (g == 0) {
      float m1 = mls[wq * 16 + ln16];
      float mM = fmaxf(m_, m1);
      float e0 = exp2n(m_ - mM), e1 = exp2n(m1 - mM);
      float e0r[4], e1r[4], ivr[4];
#pragma unroll
      for (int ri = 0; ri < 4; ++ri) {
        int src = l16 * 4 + ri;
        e0r[ri] = __shfl(e0, src);
        e1r[ri] = __shfl(e1, src);
      }
#pragma unroll
      for (int ri = 0; ri < 4; ++ri) {
        float l1 = lls[wq * 16 + l16 * 4 + ri];
        ivr[ri] = 1.f / (lacc[ri] * e0r[ri] + l1 * e1r[ri]);
      }
#pragma unroll
      for (int di = 0; di < 4; ++di)
#pragma unroll
        for (int ri = 0; ri < 4; ++ri) {
          float a1 = Od[wq * 1040 + (l16 * 4 + ri) * 65 + di * 16 + ln16];
          float o = (cacc[di][ri] * e0r[ri] + a1 * e1r[ri]) * ivr[ri];
          int row = q0 + wq * 16 + l16 * 4 + ri;
          int col = h * DHH + di * 16 + ln16;
          ctx[(size_t)(b * SS + row) * DD + col] = f2bf(o);
        }
    }
    __syncthreads();
  }
}

extern "C" void kernel_launch(void* const* d_in, const int* in_sizes, int n_in,
                              void* d_out, int out_size, void* d_ws, size_t ws_size,
                              hipStream_t stream) {
  const float* x      = (const float*)d_in[0];
  const float* w_attn = (const float*)d_in[1];
  const float* b_attn = (const float*)d_in[2];
  const float* w_proj = (const float*)d_in[3];
  const float* b_proj = (const float*)d_in[4];
  float* out = (float*)d_out;

  char* ws = (char*)d_ws;
  short* xb     = (short*)(ws);                       // 8388608 B
  short* wattnT = (short*)(ws + 8388608);             // 6291456 B
  short* wprojT = (short*)(ws + 14680064);            // 2097152 B
  short* qkv    = (short*)(ws + 16777216);            // 25165824 B (V third unused)
  short* vt     = (short*)(ws + 41943040);            // 8388608 B
  short* ctx    = (short*)(ws + 50331648);            // 8388608 B

  // fused prep: x cast + both weight transposes in one launch
  prep_k<<<5120, 256, 0, stream>>>(x, xb, w_attn, wattnT, w_proj, wprojT);
  // QKV GEMM (proven m97/128^2 structure): Q (scaled) + K to qkv, V transposed to vt
  gemm128_k<0><<<dim3(N3D / 128, MTOK / 128), 256, 0, stream>>>(xb, wattnT, b_attn, qkv, vt, MTOK, N3D, DD);
  flash_attn_k<<<dim3(512), 512, 0, stream>>>(qkv, vt, ctx);
  gemm128_k<1><<<dim3(DD / 128, MTOK / 128), 256, 0, stream>>>(ctx, wprojT, b_proj, out, nullptr, MTOK, DD, DD);
}

// Round 17
// 114.205 us; speedup vs baseline: 1.2040x; 1.0117x over previous
//
#include <hip/hip_runtime.h>
#include <hip/hip_bf16.h>

// GPT2 attention. B=2, S=2048, D=1024, H=16, DH=64.
// inputs (f32): x[2,2048,1024], w_attn[1024,3072], b_attn[3072], w_proj[1024,1024], b_proj[1024]
// output (f32): [2,2048,1024]

#define BB 2
#define SS 2048
#define DD 1024
#define HH 16
#define DHH 64
#define MTOK (BB * SS)        // 4096
#define N3D (3 * DD)          // 3072
// 1/sqrt(64) * log2(e): softmax runs in exp2 domain
#define QSCALE 0.18033688f

typedef __attribute__((ext_vector_type(8))) short bf16x8;
typedef __attribute__((ext_vector_type(4))) float f32x4;
typedef __attribute__((ext_vector_type(4))) short short4v;

__device__ __forceinline__ short f2bf(float f) {
  unsigned int x = __float_as_uint(f);
  unsigned int r = (x + 0x7fffu + ((x >> 16) & 1u)) >> 16;
  return (short)r;
}

__device__ __forceinline__ unsigned int cvtpk_bf16(float lo, float hi) {
  unsigned int r;
  asm("v_cvt_pk_bf16_f32 %0, %1, %2" : "=v"(r) : "v"(lo), "v"(hi));
  return r;
}

// native 2^x (v_exp_f32 IS exp2); plain exp2f() lowers to an ocml libcall.
__device__ __forceinline__ float exp2n(float x) {
  float r;
  asm("v_exp_f32 %0, %1" : "=v"(r) : "v"(x));
  return r;
}

// ---------------- fused prep: x cast + w_attn transpose + w_proj transpose ----------------
__global__ __launch_bounds__(256) void prep_k(const float* __restrict__ x, short* __restrict__ xb,
                                              const float* __restrict__ wa, short* __restrict__ waT,
                                              const float* __restrict__ wp, short* __restrict__ wpT) {
  __shared__ float t[32][33];
  int bid = blockIdx.x, tid = threadIdx.x;
  if (bid < 1024) {
    int base = bid * 1024 + tid;
#pragma unroll
    for (int j = 0; j < 4; ++j) {
      float4 v = reinterpret_cast<const float4*>(x)[base + 256 * j];
      short4v o;
      o[0] = f2bf(v.x); o[1] = f2bf(v.y); o[2] = f2bf(v.z); o[3] = f2bf(v.w);
      reinterpret_cast<short4v*>(xb)[base + 256 * j] = o;
    }
    return;
  }
  const float* W; short* Wt; int K, N, n0, k0;
  if (bid < 4096) {
    int id = bid - 1024;
    W = wa; Wt = waT; K = 1024; N = 3072;
    n0 = (id % 96) * 32; k0 = (id / 96) * 32;
  } else {
    int id = bid - 4096;
    W = wp; Wt = wpT; K = 1024; N = 1024;
    n0 = (id & 31) * 32; k0 = (id >> 5) * 32;
  }
  int tx = tid & 31, ty = tid >> 5;
#pragma unroll
  for (int i = 0; i < 4; ++i)
    t[ty + 8 * i][tx] = W[(size_t)(k0 + ty + 8 * i) * N + n0 + tx];
  __syncthreads();
#pragma unroll
  for (int i = 0; i < 4; ++i)
    Wt[(size_t)(n0 + ty + 8 * i) * K + k0 + tx] = f2bf(t[tx][ty + 8 * i]);
}

// ---------------- GEMM m97-structure, compile-time dims, XCD-chunked 1-D grid ----------------
// OUTF32=0 (QKV): bf16 out; Q cols (n0<DD) pre-scaled by QSCALE; V cols (n0>=2DD)
// written TRANSPOSED to vtout. OUTF32=1 (proj): f32 out.
// 1-D grid of (N/128)*(M/128) blocks, chunk-swizzled so each XCD owns a contiguous
// range of m-major tile ids (same-A-panel blocks share an XCD L2).
template <int OUTF32, int M, int N, int K>
__global__ __launch_bounds__(256) void gemm128_k(const short* __restrict__ A,
                                                 const short* __restrict__ Bt,
                                                 const float* __restrict__ bias,
                                                 void* __restrict__ Cout,
                                                 short* __restrict__ vtout) {
  __shared__ short As[128 * 64];
  __shared__ short Bs[128 * 64];
  constexpr int NX = N / 128;
  constexpr int NWG = NX * (M / 128);
  constexpr int CHUNK = NWG / 8;  // NWG % 8 == 0 for both instantiations
  int tid = threadIdx.x;
  int swz = (blockIdx.x & 7) * CHUNK + (blockIdx.x >> 3);
  int m0 = (swz / NX) * 128, n0 = (swz % NX) * 128;
  int w = tid >> 6, lane = tid & 63;
  int wr = w >> 1, wc = w & 1;
  int ln16 = lane & 15, l16 = lane >> 4;

  f32x4 acc[4][4] = {};

  int lrow0 = w * 32 + (lane >> 3);
  int blk_p = lane & 7;

#pragma unroll 1
  for (int k0 = 0; k0 < K; k0 += 64) {
#pragma unroll
    for (int i = 0; i < 4; ++i) {
      int row_p = lrow0 + i * 8;
      int colE = ((blk_p ^ (row_p & 7)) << 3);
      __builtin_amdgcn_global_load_lds(
          (const __attribute__((address_space(1))) unsigned int*)&A[(size_t)(m0 + row_p) * K + k0 + colE],
          (__attribute__((address_space(3))) unsigned int*)&As[(w * 4 + i) * 512],
          16, 0, 0);
      __builtin_amdgcn_global_load_lds(
          (const __attribute__((address_space(1))) unsigned int*)&Bt[(size_t)(n0 + row_p) * K + k0 + colE],
          (__attribute__((address_space(3))) unsigned int*)&Bs[(w * 4 + i) * 512],
          16, 0, 0);
    }
    __syncthreads();
#pragma unroll
    for (int kk = 0; kk < 2; ++kk) {
      bf16x8 a[4], bfr[4];
#pragma unroll
      for (int mi = 0; mi < 4; ++mi) {
        int row = wr * 64 + mi * 16 + ln16;
        int blk = (kk * 4 + l16) ^ (row & 7);
        a[mi] = *reinterpret_cast<const bf16x8*>(&As[row * 64 + blk * 8]);
      }
#pragma unroll
      for (int ni = 0; ni < 4; ++ni) {
        int row = wc * 64 + ni * 16 + ln16;
        int blk = (kk * 4 + l16) ^ (row & 7);
        bfr[ni] = *reinterpret_cast<const bf16x8*>(&Bs[row * 64 + blk * 8]);
      }
#pragma unroll
      for (int mi = 0; mi < 4; ++mi)
#pragma unroll
        for (int ni = 0; ni < 4; ++ni)
          acc[mi][ni] = __builtin_amdgcn_mfma_f32_16x16x32_bf16(a[mi], bfr[ni], acc[mi][ni], 0, 0, 0);
    }
    __syncthreads();
  }

#pragma unroll
  for (int mi = 0; mi < 4; ++mi)
#pragma unroll
    for (int ni = 0; ni < 4; ++ni)
#pragma unroll
      for (int ri = 0; ri < 4; ++ri) {
        int row = m0 + wr * 64 + mi * 16 + l16 * 4 + ri;
        int col = n0 + wc * 64 + ni * 16 + ln16;
        float v = acc[mi][ni][ri] + bias[col];
        if (OUTF32) {
          reinterpret_cast<float*>(Cout)[(size_t)row * N + col] = v;
        } else {
          if (n0 < DD) v *= QSCALE;  // Q block (uniform per block)
          short bv = f2bf(v);
          if (n0 >= 2 * DD) {
            // V block: write transposed to vt
            int bb = row >> 11, s = row & 2047;
            vtout[(size_t)(bb * 1024 + col - 2 * DD) * SS + s] = bv;
          } else {
            reinterpret_cast<short*>(Cout)[(size_t)row * N + col] = bv;
          }
        }
      }
}

// ---------------- Flash attention (R16: l-via-ones-MFMA, setprio, XCD swizzle) ----------------
#define MASKV -3.0e38f
__global__ __launch_bounds__(512) void flash_attn_k(const short* __restrict__ qkv,
                                                    const short* __restrict__ vt,
                                                    short* __restrict__ ctx) {
  __shared__ __align__(16) char smem[53248];
  // [0,18432): Ks[2][64][72] ; [18432,36864): Vs[2][64][72] ; [36864,53248): Ps 8*16*64 shorts
  // (XOR-swizzled 16B blocks). Combine aliases: Od f32 dump at [0,16640), mls at [17408,17920),
  // lls (l dump, cacc-row layout) at [17920,18432).
  short (*Ks)[64][72] = reinterpret_cast<short(*)[64][72]>(smem);
  short (*Vs)[64][72] = reinterpret_cast<short(*)[64][72]>(smem + 18432);
  short* Psr = reinterpret_cast<short*>(smem + 36864);
  float* Od = reinterpret_cast<float*>(smem);
  float* mls = reinterpret_cast<float*>(smem + 17408);
  float* lls = reinterpret_cast<float*>(smem + 17920);

  int tid = threadIdx.x;
  // XCD-chunked swizzle: same-head blocks share an XCD L2.
  int orig = blockIdx.x;                    // 0..511
  int wg = (orig & 7) * 64 + (orig >> 3);   // bijective (512 % 8 == 0)
  int bh = wg >> 4;
  int pj = wg & 15;
  int b = bh >> 4, h = bh & 15;
  int wgv = tid >> 6, lane = tid & 63;
  int g = wgv >> 2, wq = wgv & 3;
  int ln16 = lane & 15, l16 = lane >> 4;
  int t8 = tid & 255;
  int tb = tid >> 8;  // staging parity buffer this thread fills
  int r0 = t8 >> 3, cc0 = (t8 & 7) << 3;
  int psq = (wgv << 10) + (ln16 << 6);  // Ps base (shorts) for this wave+q

  // all-ones bf16x8 (1.0 = 0x3F80) for the l row-sum MFMA
  bf16x8 vone;
#pragma unroll
  for (int j = 0; j < 8; ++j) vone[j] = (short)0x3F80;

  const short* kbase = qkv + (size_t)(b * SS) * N3D + DD + h * DHH;  // + s*N3D + d
  const short* vbase = vt + (size_t)(bh * DHH) * SS;                 // + d*SS + s

#pragma unroll 1
  for (int ti = 0; ti < 2; ++ti) {
    int qt = ti ? pj : 31 - pj;
    int q0 = qt * 64;

    bf16x8 qf[2];
    {
      const short* qrow = qkv + (size_t)(b * SS + q0 + wq * 16 + ln16) * N3D + h * DHH;
      qf[0] = *reinterpret_cast<const bf16x8*>(qrow + l16 * 8);
      qf[1] = *reinterpret_cast<const bf16x8*>(qrow + 32 + l16 * 8);
    }
    float m_ = -1e30f;
    f32x4 cacc[4] = {};
    f32x4 lacc = {};

    int ns = (qt + 2) >> 1;
    uint4 kr0, kr1, vr0, vr1;
    {
      int kt_s = tb <= qt ? tb : qt;
      kr0 = *reinterpret_cast<const uint4*>(kbase + (size_t)(kt_s * 64 + r0) * N3D + cc0);
      kr1 = *reinterpret_cast<const uint4*>(kbase + (size_t)(kt_s * 64 + r0 + 32) * N3D + cc0);
      vr0 = *reinterpret_cast<const uint4*>(vbase + (size_t)r0 * SS + kt_s * 64 + cc0);
      vr1 = *reinterpret_cast<const uint4*>(vbase + (size_t)(r0 + 32) * SS + kt_s * 64 + cc0);
    }

#pragma unroll 1
    for (int s = 0; s < ns; ++s) {
      *reinterpret_cast<uint4*>(&Ks[tb][r0][cc0]) = kr0;
      *reinterpret_cast<uint4*>(&Ks[tb][r0 + 32][cc0]) = kr1;
      *reinterpret_cast<uint4*>(&Vs[tb][r0][cc0]) = vr0;
      *reinterpret_cast<uint4*>(&Vs[tb][r0 + 32][cc0]) = vr1;
      __syncthreads();

      // prefetch next super-iter (clamped; latency hides under softmax+PV)
      {
        int kt_n = 2 * (s + 1) + tb;
        if (kt_n > qt) kt_n = qt;
        kr0 = *reinterpret_cast<const uint4*>(kbase + (size_t)(kt_n * 64 + r0) * N3D + cc0);
        kr1 = *reinterpret_cast<const uint4*>(kbase + (size_t)(kt_n * 64 + r0 + 32) * N3D + cc0);
        vr0 = *reinterpret_cast<const uint4*>(vbase + (size_t)r0 * SS + kt_n * 64 + cc0);
        vr1 = *reinterpret_cast<const uint4*>(vbase + (size_t)(r0 + 32) * SS + kt_n * 64 + cc0);
      }

      int kt_c = 2 * s + g;
      if (kt_c <= qt) {
        // QK^T swapped: sacc[ni][ri] = S^T[k = ni*16+l16*4+ri][q = ln16]  (log2-scaled)
        f32x4 sacc[4] = {};
        __builtin_amdgcn_s_setprio(1);
#pragma unroll
        for (int kk = 0; kk < 2; ++kk)
#pragma unroll
          for (int ni = 0; ni < 4; ++ni) {
            bf16x8 kf = *reinterpret_cast<const bf16x8*>(&Ks[g][ni * 16 + ln16][kk * 32 + l16 * 8]);
            sacc[ni] = __builtin_amdgcn_mfma_f32_16x16x32_bf16(kf, qf[kk], sacc[ni], 0, 0, 0);
          }
        __builtin_amdgcn_s_setprio(0);

        float p[4][4];
        float mx = MASKV;
        if (kt_c == qt) {  // diagonal tile: causal mask
          int qg = q0 + wq * 16 + ln16;
#pragma unroll
          for (int ni = 0; ni < 4; ++ni)
#pragma unroll
            for (int ri = 0; ri < 4; ++ri) {
              int kg = kt_c * 64 + ni * 16 + l16 * 4 + ri;
              float v = (kg > qg) ? MASKV : sacc[ni][ri];
              p[ni][ri] = v;
              mx = fmaxf(mx, v);
            }
        } else {
#pragma unroll
          for (int ni = 0; ni < 4; ++ni)
#pragma unroll
            for (int ri = 0; ri < 4; ++ri) {
              p[ni][ri] = sacc[ni][ri];
              mx = fmaxf(mx, sacc[ni][ri]);
            }
        }
        mx = fmaxf(mx, __shfl_xor(mx, 16));
        mx = fmaxf(mx, __shfl_xor(mx, 32));

        // defer-max (T13), log2 domain: rescale only when max grew by > 11.5
        int keep = __all(mx <= m_ + 11.5f);
        float mn = m_;
        if (!keep) {
          mn = fmaxf(m_, mx);
          float sc = exp2n(m_ - mn);
          float scr[4];
#pragma unroll
          for (int ri = 0; ri < 4; ++ri) scr[ri] = __shfl(sc, l16 * 4 + ri);
#pragma unroll
          for (int di = 0; di < 4; ++di)
#pragma unroll
            for (int ri = 0; ri < 4; ++ri) cacc[di][ri] *= scr[ri];
#pragma unroll
          for (int ri = 0; ri < 4; ++ri) lacc[ri] *= scr[ri];
          m_ = mn;
        }

#pragma unroll
        for (int ni = 0; ni < 4; ++ni)
#pragma unroll
          for (int ri = 0; ri < 4; ++ri)
            p[ni][ri] = exp2n(p[ni][ri] - mn);

        // pack P -> Ps[wave][q=ln16][k], XOR-swizzled 16B blocks (blk ^= q&7)
#pragma unroll
        for (int ni = 0; ni < 4; ++ni) {
          uint2 u;
          u.x = cvtpk_bf16(p[ni][0], p[ni][1]);
          u.y = cvtpk_bf16(p[ni][2], p[ni][3]);
          int idx = psq + ((((ni << 1) + (l16 >> 1)) ^ (ln16 & 7)) << 3) + ((l16 & 1) << 2);
          *reinterpret_cast<uint2*>(&Psr[idx]) = u;
        }
        asm volatile("s_waitcnt lgkmcnt(0)" ::: "memory");

        // ctx += P @ V ; l += P @ ones (same C-layout: row = l16*4+ri)
        __builtin_amdgcn_s_setprio(1);
#pragma unroll
        for (int kk = 0; kk < 2; ++kk) {
          bf16x8 pa = *reinterpret_cast<const bf16x8*>(
              &Psr[psq + ((((kk << 2) + l16) ^ (ln16 & 7)) << 3)]);
          lacc = __builtin_amdgcn_mfma_f32_16x16x32_bf16(pa, vone, lacc, 0, 0, 0);
#pragma unroll
          for (int di = 0; di < 4; ++di) {
            bf16x8 vb = *reinterpret_cast<const bf16x8*>(&Vs[g][di * 16 + ln16][kk * 32 + l16 * 8]);
            cacc[di] = __builtin_amdgcn_mfma_f32_16x16x32_bf16(pa, vb, cacc[di], 0, 0, 0);
          }
        }
        __builtin_amdgcn_s_setprio(0);
      }
      __syncthreads();
    }

    // ---- combine even/odd partials (aliases Ks/Vs region; all kv reads done) ----
    if (g == 1) {
      if (l16 == 0) mls[wq * 16 + ln16] = m_;
      if (ln16 == 0)
#pragma unroll
        for (int ri = 0; ri < 4; ++ri) lls[wq * 16 + l16 * 4 + ri] = lacc[ri];
#pragma unroll
      for (int di = 0; di < 4; ++di)
#pragma unroll
        for (int ri = 0; ri < 4; ++ri)
          Od[wq * 1040 + (l16 * 4 + ri) * 65 + di * 16 + ln16] = cacc[di][ri];
    }
    __syncthreads();
    if (g == 0) {
      float m1 = mls[wq * 16 + ln16];
      float mM = fmaxf(m_, m1);
      float e0 = exp2n(m_ - mM), e1 = exp2n(m1 - mM);
      float e0r[4], e1r[4], ivr[4];
#pragma unroll
      for (int ri = 0; ri < 4; ++ri) {
        int src = l16 * 4 + ri;
        e0r[ri] = __shfl(e0, src);
        e1r[ri] = __shfl(e1, src);
      }
#pragma unroll
      for (int ri = 0; ri < 4; ++ri) {
        float l1 = lls[wq * 16 + l16 * 4 + ri];
        ivr[ri] = 1.f / (lacc[ri] * e0r[ri] + l1 * e1r[ri]);
      }
#pragma unroll
      for (int di = 0; di < 4; ++di)
#pragma unroll
        for (int ri = 0; ri < 4; ++ri) {
          float a1 = Od[wq * 1040 + (l16 * 4 + ri) * 65 + di * 16 + ln16];
          float o = (cacc[di][ri] * e0r[ri] + a1 * e1r[ri]) * ivr[ri];
          int row = q0 + wq * 16 + l16 * 4 + ri;
          int col = h * DHH + di * 16 + ln16;
          ctx[(size_t)(b * SS + row) * DD + col] = f2bf(o);
        }
    }
    __syncthreads();
  }
}

extern "C" void kernel_launch(void* const* d_in, const int* in_sizes, int n_in,
                              void* d_out, int out_size, void* d_ws, size_t ws_size,
                              hipStream_t stream) {
  const float* x      = (const float*)d_in[0];
  const float* w_attn = (const float*)d_in[1];
  const float* b_attn = (const float*)d_in[2];
  const float* w_proj = (const float*)d_in[3];
  const float* b_proj = (const float*)d_in[4];
  float* out = (float*)d_out;

  char* ws = (char*)d_ws;
  short* xb     = (short*)(ws);                       // 8388608 B
  short* wattnT = (short*)(ws + 8388608);             // 6291456 B
  short* wprojT = (short*)(ws + 14680064);            // 2097152 B
  short* qkv    = (short*)(ws + 16777216);            // 25165824 B (V third unused)
  short* vt     = (short*)(ws + 41943040);            // 8388608 B
  short* ctx    = (short*)(ws + 50331648);            // 8388608 B

  // fused prep: x cast + both weight transposes in one launch
  prep_k<<<5120, 256, 0, stream>>>(x, xb, w_attn, wattnT, w_proj, wprojT);
  // QKV GEMM: Q (scaled) + K to qkv, V transposed to vt. 1-D XCD-chunked grid.
  gemm128_k<0, MTOK, N3D, DD><<<(N3D / 128) * (MTOK / 128), 256, 0, stream>>>(
      xb, wattnT, b_attn, qkv, vt);
  flash_attn_k<<<dim3(512), 512, 0, stream>>>(qkv, vt, ctx);
  gemm128_k<1, MTOK, DD, DD><<<(DD / 128) * (MTOK / 128), 256, 0, stream>>>(
      ctx, wprojT, b_proj, out, nullptr);
}

// Round 18
// 114.184 us; speedup vs baseline: 1.2042x; 1.0002x over previous
//
#include <hip/hip_runtime.h>
#include <hip/hip_bf16.h>

// GPT2 attention. B=2, S=2048, D=1024, H=16, DH=64.
// inputs (f32): x[2,2048,1024], w_attn[1024,3072], b_attn[3072], w_proj[1024,1024], b_proj[1024]
// output (f32): [2,2048,1024]

#define BB 2
#define SS 2048
#define DD 1024
#define HH 16
#define DHH 64
#define MTOK (BB * SS)        // 4096
#define N3D (3 * DD)          // 3072
// 1/sqrt(64) * log2(e): softmax runs in exp2 domain
#define QSCALE 0.18033688f

typedef __attribute__((ext_vector_type(8))) short bf16x8;
typedef __attribute__((ext_vector_type(4))) float f32x4;
typedef __attribute__((ext_vector_type(4))) short short4v;

__device__ __forceinline__ short f2bf(float f) {
  unsigned int x = __float_as_uint(f);
  unsigned int r = (x + 0x7fffu + ((x >> 16) & 1u)) >> 16;
  return (short)r;
}

__device__ __forceinline__ unsigned int cvtpk_bf16(float lo, float hi) {
  unsigned int r;
  asm("v_cvt_pk_bf16_f32 %0, %1, %2" : "=v"(r) : "v"(lo), "v"(hi));
  return r;
}

// native 2^x (v_exp_f32 IS exp2); plain exp2f() lowers to an ocml libcall.
__device__ __forceinline__ float exp2n(float x) {
  float r;
  asm("v_exp_f32 %0, %1" : "=v"(r) : "v"(x));
  return r;
}

// ---------------- fused prep: x cast + w_attn transpose + w_proj transpose ----------------
__global__ __launch_bounds__(256) void prep_k(const float* __restrict__ x, short* __restrict__ xb,
                                              const float* __restrict__ wa, short* __restrict__ waT,
                                              const float* __restrict__ wp, short* __restrict__ wpT) {
  __shared__ float t[32][33];
  int bid = blockIdx.x, tid = threadIdx.x;
  if (bid < 1024) {
    int base = bid * 1024 + tid;
#pragma unroll
    for (int j = 0; j < 4; ++j) {
      float4 v = reinterpret_cast<const float4*>(x)[base + 256 * j];
      short4v o;
      o[0] = f2bf(v.x); o[1] = f2bf(v.y); o[2] = f2bf(v.z); o[3] = f2bf(v.w);
      reinterpret_cast<short4v*>(xb)[base + 256 * j] = o;
    }
    return;
  }
  const float* W; short* Wt; int K, N, n0, k0;
  if (bid < 4096) {
    int id = bid - 1024;
    W = wa; Wt = waT; K = 1024; N = 3072;
    n0 = (id % 96) * 32; k0 = (id / 96) * 32;
  } else {
    int id = bid - 4096;
    W = wp; Wt = wpT; K = 1024; N = 1024;
    n0 = (id & 31) * 32; k0 = (id >> 5) * 32;
  }
  int tx = tid & 31, ty = tid >> 5;
#pragma unroll
  for (int i = 0; i < 4; ++i)
    t[ty + 8 * i][tx] = W[(size_t)(k0 + ty + 8 * i) * N + n0 + tx];
  __syncthreads();
#pragma unroll
  for (int i = 0; i < 4; ++i)
    Wt[(size_t)(n0 + ty + 8 * i) * K + k0 + tx] = f2bf(t[tx][ty + 8 * i]);
}

// ---------------- GEMM m97-structure, compile-time dims, XCD-chunked 1-D grid ----------------
// OUTF32=0 (QKV): bf16 out; Q cols (n0<DD) pre-scaled by QSCALE; V cols (n0>=2DD)
// written TRANSPOSED to vtout. OUTF32=1 (proj): f32 out.
template <int OUTF32, int M, int N, int K>
__global__ __launch_bounds__(256) void gemm128_k(const short* __restrict__ A,
                                                 const short* __restrict__ Bt,
                                                 const float* __restrict__ bias,
                                                 void* __restrict__ Cout,
                                                 short* __restrict__ vtout) {
  __shared__ short As[128 * 64];
  __shared__ short Bs[128 * 64];
  constexpr int NX = N / 128;
  constexpr int NWG = NX * (M / 128);
  constexpr int CHUNK = NWG / 8;  // NWG % 8 == 0 for both instantiations
  int tid = threadIdx.x;
  int swz = (blockIdx.x & 7) * CHUNK + (blockIdx.x >> 3);
  int m0 = (swz / NX) * 128, n0 = (swz % NX) * 128;
  int w = tid >> 6, lane = tid & 63;
  int wr = w >> 1, wc = w & 1;
  int ln16 = lane & 15, l16 = lane >> 4;

  f32x4 acc[4][4] = {};

  int lrow0 = w * 32 + (lane >> 3);
  int blk_p = lane & 7;

#pragma unroll 1
  for (int k0 = 0; k0 < K; k0 += 64) {
#pragma unroll
    for (int i = 0; i < 4; ++i) {
      int row_p = lrow0 + i * 8;
      int colE = ((blk_p ^ (row_p & 7)) << 3);
      __builtin_amdgcn_global_load_lds(
          (const __attribute__((address_space(1))) unsigned int*)&A[(size_t)(m0 + row_p) * K + k0 + colE],
          (__attribute__((address_space(3))) unsigned int*)&As[(w * 4 + i) * 512],
          16, 0, 0);
      __builtin_amdgcn_global_load_lds(
          (const __attribute__((address_space(1))) unsigned int*)&Bt[(size_t)(n0 + row_p) * K + k0 + colE],
          (__attribute__((address_space(3))) unsigned int*)&Bs[(w * 4 + i) * 512],
          16, 0, 0);
    }
    __syncthreads();
#pragma unroll
    for (int kk = 0; kk < 2; ++kk) {
      bf16x8 a[4], bfr[4];
#pragma unroll
      for (int mi = 0; mi < 4; ++mi) {
        int row = wr * 64 + mi * 16 + ln16;
        int blk = (kk * 4 + l16) ^ (row & 7);
        a[mi] = *reinterpret_cast<const bf16x8*>(&As[row * 64 + blk * 8]);
      }
#pragma unroll
      for (int ni = 0; ni < 4; ++ni) {
        int row = wc * 64 + ni * 16 + ln16;
        int blk = (kk * 4 + l16) ^ (row & 7);
        bfr[ni] = *reinterpret_cast<const bf16x8*>(&Bs[row * 64 + blk * 8]);
      }
#pragma unroll
      for (int mi = 0; mi < 4; ++mi)
#pragma unroll
        for (int ni = 0; ni < 4; ++ni)
          acc[mi][ni] = __builtin_amdgcn_mfma_f32_16x16x32_bf16(a[mi], bfr[ni], acc[mi][ni], 0, 0, 0);
    }
    __syncthreads();
  }

#pragma unroll
  for (int mi = 0; mi < 4; ++mi)
#pragma unroll
    for (int ni = 0; ni < 4; ++ni)
#pragma unroll
      for (int ri = 0; ri < 4; ++ri) {
        int row = m0 + wr * 64 + mi * 16 + l16 * 4 + ri;
        int col = n0 + wc * 64 + ni * 16 + ln16;
        float v = acc[mi][ni][ri] + bias[col];
        if (OUTF32) {
          reinterpret_cast<float*>(Cout)[(size_t)row * N + col] = v;
        } else {
          if (n0 < DD) v *= QSCALE;  // Q block (uniform per block)
          short bv = f2bf(v);
          if (n0 >= 2 * DD) {
            // V block: write transposed to vt
            int bb = row >> 11, s = row & 2047;
            vtout[(size_t)(bb * 1024 + col - 2 * DD) * SS + s] = bv;
          } else {
            reinterpret_cast<short*>(Cout)[(size_t)row * N + col] = bv;
          }
        }
      }
}

// ---------------- Flash attention (R17 + pack/PV interleave + tree max) ----------------
// 1-D grid of 512 blocks, 512 threads, XCD-chunked swizzle. Waves 0-3 (g=0): even kt;
// waves 4-7 (g=1): odd kt. Wave wq owns q-rows [wq*16, wq*16+16). Block does q-tiles
// 31-pj then pj (uniform work). l via mfma(pa, ones). log2-domain softmax (native v_exp).
// Pack->PV now interleaved at kk granularity: pack(ni0,1) -> wait -> PV(kk0) runs while
// pack(ni2,3) issues -> wait -> PV(kk1). LDS 53248 B.
#define MASKV -3.0e38f
__global__ __launch_bounds__(512) void flash_attn_k(const short* __restrict__ qkv,
                                                    const short* __restrict__ vt,
                                                    short* __restrict__ ctx) {
  __shared__ __align__(16) char smem[53248];
  // [0,18432): Ks[2][64][72] ; [18432,36864): Vs[2][64][72] ; [36864,53248): Ps 8*16*64 shorts
  // (XOR-swizzled 16B blocks). Combine aliases: Od f32 dump at [0,16640), mls at [17408,17920),
  // lls (l dump, cacc-row layout) at [17920,18432).
  short (*Ks)[64][72] = reinterpret_cast<short(*)[64][72]>(smem);
  short (*Vs)[64][72] = reinterpret_cast<short(*)[64][72]>(smem + 18432);
  short* Psr = reinterpret_cast<short*>(smem + 36864);
  float* Od = reinterpret_cast<float*>(smem);
  float* mls = reinterpret_cast<float*>(smem + 17408);
  float* lls = reinterpret_cast<float*>(smem + 17920);

  int tid = threadIdx.x;
  // XCD-chunked swizzle: same-head blocks share an XCD L2.
  int orig = blockIdx.x;                    // 0..511
  int wg = (orig & 7) * 64 + (orig >> 3);   // bijective (512 % 8 == 0)
  int bh = wg >> 4;
  int pj = wg & 15;
  int b = bh >> 4, h = bh & 15;
  int wgv = tid >> 6, lane = tid & 63;
  int g = wgv >> 2, wq = wgv & 3;
  int ln16 = lane & 15, l16 = lane >> 4;
  int t8 = tid & 255;
  int tb = tid >> 8;  // staging parity buffer this thread fills
  int r0 = t8 >> 3, cc0 = (t8 & 7) << 3;
  int psq = (wgv << 10) + (ln16 << 6);  // Ps base (shorts) for this wave+q

  // all-ones bf16x8 (1.0 = 0x3F80) for the l row-sum MFMA
  bf16x8 vone;
#pragma unroll
  for (int j = 0; j < 8; ++j) vone[j] = (short)0x3F80;

  const short* kbase = qkv + (size_t)(b * SS) * N3D + DD + h * DHH;  // + s*N3D + d
  const short* vbase = vt + (size_t)(bh * DHH) * SS;                 // + d*SS + s

#pragma unroll 1
  for (int ti = 0; ti < 2; ++ti) {
    int qt = ti ? pj : 31 - pj;
    int q0 = qt * 64;

    bf16x8 qf[2];
    {
      const short* qrow = qkv + (size_t)(b * SS + q0 + wq * 16 + ln16) * N3D + h * DHH;
      qf[0] = *reinterpret_cast<const bf16x8*>(qrow + l16 * 8);
      qf[1] = *reinterpret_cast<const bf16x8*>(qrow + 32 + l16 * 8);
    }
    float m_ = -1e30f;
    f32x4 cacc[4] = {};
    f32x4 lacc = {};

    int ns = (qt + 2) >> 1;
    uint4 kr0, kr1, vr0, vr1;
    {
      int kt_s = tb <= qt ? tb : qt;
      kr0 = *reinterpret_cast<const uint4*>(kbase + (size_t)(kt_s * 64 + r0) * N3D + cc0);
      kr1 = *reinterpret_cast<const uint4*>(kbase + (size_t)(kt_s * 64 + r0 + 32) * N3D + cc0);
      vr0 = *reinterpret_cast<const uint4*>(vbase + (size_t)r0 * SS + kt_s * 64 + cc0);
      vr1 = *reinterpret_cast<const uint4*>(vbase + (size_t)(r0 + 32) * SS + kt_s * 64 + cc0);
    }

#pragma unroll 1
    for (int s = 0; s < ns; ++s) {
      *reinterpret_cast<uint4*>(&Ks[tb][r0][cc0]) = kr0;
      *reinterpret_cast<uint4*>(&Ks[tb][r0 + 32][cc0]) = kr1;
      *reinterpret_cast<uint4*>(&Vs[tb][r0][cc0]) = vr0;
      *reinterpret_cast<uint4*>(&Vs[tb][r0 + 32][cc0]) = vr1;
      __syncthreads();

      // prefetch next super-iter (clamped; latency hides under softmax+PV)
      {
        int kt_n = 2 * (s + 1) + tb;
        if (kt_n > qt) kt_n = qt;
        kr0 = *reinterpret_cast<const uint4*>(kbase + (size_t)(kt_n * 64 + r0) * N3D + cc0);
        kr1 = *reinterpret_cast<const uint4*>(kbase + (size_t)(kt_n * 64 + r0 + 32) * N3D + cc0);
        vr0 = *reinterpret_cast<const uint4*>(vbase + (size_t)r0 * SS + kt_n * 64 + cc0);
        vr1 = *reinterpret_cast<const uint4*>(vbase + (size_t)(r0 + 32) * SS + kt_n * 64 + cc0);
      }

      int kt_c = 2 * s + g;
      if (kt_c <= qt) {
        // QK^T swapped: sacc[ni][ri] = S^T[k = ni*16+l16*4+ri][q = ln16]  (log2-scaled)
        f32x4 sacc[4] = {};
        __builtin_amdgcn_s_setprio(1);
#pragma unroll
        for (int kk = 0; kk < 2; ++kk)
#pragma unroll
          for (int ni = 0; ni < 4; ++ni) {
            bf16x8 kf = *reinterpret_cast<const bf16x8*>(&Ks[g][ni * 16 + ln16][kk * 32 + l16 * 8]);
            sacc[ni] = __builtin_amdgcn_mfma_f32_16x16x32_bf16(kf, qf[kk], sacc[ni], 0, 0, 0);
          }
        __builtin_amdgcn_s_setprio(0);

        float p[4][4];
        if (kt_c == qt) {  // diagonal tile: causal mask
          int qg = q0 + wq * 16 + ln16;
#pragma unroll
          for (int ni = 0; ni < 4; ++ni)
#pragma unroll
            for (int ri = 0; ri < 4; ++ri) {
              int kg = kt_c * 64 + ni * 16 + l16 * 4 + ri;
              p[ni][ri] = (kg > qg) ? MASKV : sacc[ni][ri];
            }
        } else {
#pragma unroll
          for (int ni = 0; ni < 4; ++ni)
#pragma unroll
            for (int ri = 0; ri < 4; ++ri)
              p[ni][ri] = sacc[ni][ri];
        }
        // tree max (4-wide ILP; max3-fusable) instead of 16-deep serial chain
        float r0m[4];
#pragma unroll
        for (int ni = 0; ni < 4; ++ni)
          r0m[ni] = fmaxf(fmaxf(p[ni][0], p[ni][1]), fmaxf(p[ni][2], p[ni][3]));
        float mx = fmaxf(fmaxf(r0m[0], r0m[1]), fmaxf(r0m[2], r0m[3]));
        mx = fmaxf(mx, __shfl_xor(mx, 16));
        mx = fmaxf(mx, __shfl_xor(mx, 32));

        // defer-max (T13), log2 domain: rescale only when max grew by > 11.5
        int keep = __all(mx <= m_ + 11.5f);
        float mn = m_;
        if (!keep) {
          mn = fmaxf(m_, mx);
          float sc = exp2n(m_ - mn);
          float scr[4];
#pragma unroll
          for (int ri = 0; ri < 4; ++ri) scr[ri] = __shfl(sc, l16 * 4 + ri);
#pragma unroll
          for (int di = 0; di < 4; ++di)
#pragma unroll
            for (int ri = 0; ri < 4; ++ri) cacc[di][ri] *= scr[ri];
#pragma unroll
          for (int ri = 0; ri < 4; ++ri) lacc[ri] *= scr[ri];
          m_ = mn;
        }

#pragma unroll
        for (int ni = 0; ni < 4; ++ni)
#pragma unroll
          for (int ri = 0; ri < 4; ++ri)
            p[ni][ri] = exp2n(p[ni][ri] - mn);

        // pack/PV interleaved at kk granularity: PV(kk0) overlaps pack(kk1)
#pragma unroll
        for (int kk = 0; kk < 2; ++kk) {
#pragma unroll
          for (int nj = 0; nj < 2; ++nj) {
            int ni = 2 * kk + nj;
            uint2 u;
            u.x = cvtpk_bf16(p[ni][0], p[ni][1]);
            u.y = cvtpk_bf16(p[ni][2], p[ni][3]);
            int idx = psq + ((((ni << 1) + (l16 >> 1)) ^ (ln16 & 7)) << 3) + ((l16 & 1) << 2);
            *reinterpret_cast<uint2*>(&Psr[idx]) = u;
          }
          asm volatile("s_waitcnt lgkmcnt(0)" ::: "memory");
          bf16x8 pa = *reinterpret_cast<const bf16x8*>(
              &Psr[psq + ((((kk << 2) + l16) ^ (ln16 & 7)) << 3)]);
          __builtin_amdgcn_s_setprio(1);
          lacc = __builtin_amdgcn_mfma_f32_16x16x32_bf16(pa, vone, lacc, 0, 0, 0);
#pragma unroll
          for (int di = 0; di < 4; ++di) {
            bf16x8 vb = *reinterpret_cast<const bf16x8*>(&Vs[g][di * 16 + ln16][kk * 32 + l16 * 8]);
            cacc[di] = __builtin_amdgcn_mfma_f32_16x16x32_bf16(pa, vb, cacc[di], 0, 0, 0);
          }
          __builtin_amdgcn_s_setprio(0);
        }
      }
      __syncthreads();
    }

    // ---- combine even/odd partials (aliases Ks/Vs region; all kv reads done) ----
    if (g == 1) {
      if (l16 == 0) mls[wq * 16 + ln16] = m_;
      if (ln16 == 0)
#pragma unroll
        for (int ri = 0; ri < 4; ++ri) lls[wq * 16 + l16 * 4 + ri] = lacc[ri];
#pragma unroll
      for (int di = 0; di < 4; ++di)
#pragma unroll
        for (int ri = 0; ri < 4; ++ri)
          Od[wq * 1040 + (l16 * 4 + ri) * 65 + di * 16 + ln16] = cacc[di][ri];
    }
    __syncthreads();
    if (g == 0) {
      float m1 = mls[wq * 16 + ln16];
      float mM = fmaxf(m_, m1);
      float e0 = exp2n(m_ - mM), e1 = exp2n(m1 - mM);
      float e0r[4], e1r[4], ivr[4];
#pragma unroll
      for (int ri = 0; ri < 4; ++ri) {
        int src = l16 * 4 + ri;
        e0r[ri] = __shfl(e0, src);
        e1r[ri] = __shfl(e1, src);
      }
#pragma unroll
      for (int ri = 0; ri < 4; ++ri) {
        float l1 = lls[wq * 16 + l16 * 4 + ri];
        ivr[ri] = 1.f / (lacc[ri] * e0r[ri] + l1 * e1r[ri]);
      }
#pragma unroll
      for (int di = 0; di < 4; ++di)
#pragma unroll
        for (int ri = 0; ri < 4; ++ri) {
          float a1 = Od[wq * 1040 + (l16 * 4 + ri) * 65 + di * 16 + ln16];
          float o = (cacc[di][ri] * e0r[ri] + a1 * e1r[ri]) * ivr[ri];
          int row = q0 + wq * 16 + l16 * 4 + ri;
          int col = h * DHH + di * 16 + ln16;
          ctx[(size_t)(b * SS + row) * DD + col] = f2bf(o);
        }
    }
    __syncthreads();
  }
}

extern "C" void kernel_launch(void* const* d_in, const int* in_sizes, int n_in,
                              void* d_out, int out_size, void* d_ws, size_t ws_size,
                              hipStream_t stream) {
  const float* x      = (const float*)d_in[0];
  const float* w_attn = (const float*)d_in[1];
  const float* b_attn = (const float*)d_in[2];
  const float* w_proj = (const float*)d_in[3];
  const float* b_proj = (const float*)d_in[4];
  float* out = (float*)d_out;

  char* ws = (char*)d_ws;
  short* xb     = (short*)(ws);                       // 8388608 B
  short* wattnT = (short*)(ws + 8388608);             // 6291456 B
  short* wprojT = (short*)(ws + 14680064);            // 2097152 B
  short* qkv    = (short*)(ws + 16777216);            // 25165824 B (V third unused)
  short* vt     = (short*)(ws + 41943040);            // 8388608 B
  short* ctx    = (short*)(ws + 50331648);            // 8388608 B

  // fused prep: x cast + both weight transposes in one launch
  prep_k<<<5120, 256, 0, stream>>>(x, xb, w_attn, wattnT, w_proj, wprojT);
  // QKV GEMM: Q (scaled) + K to qkv, V transposed to vt. 1-D XCD-chunked grid.
  gemm128_k<0, MTOK, N3D, DD><<<(N3D / 128) * (MTOK / 128), 256, 0, stream>>>(
      xb, wattnT, b_attn, qkv, vt);
  flash_attn_k<<<dim3(512), 512, 0, stream>>>(qkv, vt, ctx);
  gemm128_k<1, MTOK, DD, DD><<<(DD / 128) * (MTOK / 128), 256, 0, stream>>>(
      ctx, wprojT, b_proj, out, nullptr);
}